// Round 4
// baseline (406.075 us; speedup 1.0000x reference)
//
#include <hip/hip_runtime.h>

typedef unsigned short u16;
typedef __attribute__((ext_vector_type(8))) __bf16 bf16x8;
typedef __attribute__((ext_vector_type(8))) u16 u16x8;
typedef __attribute__((ext_vector_type(4))) float f32x4;

#define DEVI static __device__ __forceinline__

// B=2, S=2048, D=2048, HQ=32, HKV=8, HD=64, G=4, KV_DIM=512, M=B*S=4096
// Device inputs: f32 (+ int32 mask, unused). Device outputs: f32 (out,K,V concat);
// bf16 tolerance policy (floor_eps_k=8) permits bf16 MFMA internals.

DEVI u16 f2bf(float f) {
  unsigned u = __float_as_uint(f);
  u += 0x7fff + ((u >> 16) & 1);   // RNE
  return (u16)(u >> 16);
}

DEVI float bf2f(u16 b) { return __uint_as_float(((unsigned)b) << 16); }

DEVI void gll16(const void* g, void* l) {
  __builtin_amdgcn_global_load_lds((const __attribute__((address_space(1))) void*)g,
                                   (__attribute__((address_space(3))) void*)l, 16, 0, 0);
}

// Stage 128x32 bf16 tile, LINEAR LDS (m97 pattern): slot c <- G[c>>2][(c&3)*8 ..+7]
DEVI void stage128x32(const u16* g, int ld, u16* lds) {
  int t = threadIdx.x, w = t >> 6, l = t & 63;
#pragma unroll
  for (int r = 0; r < 2; ++r) {
    int c = (w * 2 + r) * 64 + l;
    gll16(g + (size_t)(c >> 2) * ld + (c & 3) * 8, (char*)lds + (w * 2 + r) * 1024);
  }
}

// Stage 64x64 bf16 tile, LINEAR LDS: slot c <- G[c>>3][(c&7)*8 ..+7]
DEVI void stage64x64(const u16* g, int ld, u16* lds) {
  int t = threadIdx.x, w = t >> 6, l = t & 63;
#pragma unroll
  for (int r = 0; r < 2; ++r) {
    int c = (w * 2 + r) * 64 + l;
    gll16(g + (size_t)(c >> 3) * ld + (c & 7) * 8, (char*)lds + (w * 2 + r) * 1024);
  }
}

// 128x128 tile GEMM: C = A[m0:,:K] * Bt[n0:,:K]^T. 4 waves 2x2, each 64x64 (4x4 frags).
DEVI void gemm_tile(const u16* A, int lda, const u16* Bt, int ldb, int K,
                    int m0, int n0, u16* sA, u16* sB, f32x4 acc[4][4]) {
  const int t = threadIdx.x, w = t >> 6, lane = t & 63;
  const int wr = w >> 1, wc = w & 1, g = lane >> 4, r16 = lane & 15;
  int offa[4], offb[4];
#pragma unroll
  for (int m = 0; m < 4; ++m) offa[m] = (wr * 64 + m * 16 + r16) * 32 + g * 8;
#pragma unroll
  for (int n = 0; n < 4; ++n) offb[n] = (wc * 64 + n * 16 + r16) * 32 + g * 8;
#pragma unroll
  for (int m = 0; m < 4; ++m)
#pragma unroll
    for (int n = 0; n < 4; ++n) acc[m][n] = f32x4{0.f, 0.f, 0.f, 0.f};

  const u16* At = A + (size_t)m0 * lda;
  const u16* Bb = Bt + (size_t)n0 * ldb;
  stage128x32(At, lda, sA);
  stage128x32(Bb, ldb, sB);
  asm volatile("s_waitcnt vmcnt(0)" ::: "memory");
  __syncthreads();
  const int nk = K >> 5;
  int cur = 0;
  for (int kt = 0; kt < nk; ++kt) {
    if (kt + 1 < nk) {
      stage128x32(At + (kt + 1) * 32, lda, sA + (cur ^ 1) * 4096);
      stage128x32(Bb + (kt + 1) * 32, ldb, sB + (cur ^ 1) * 4096);
    }
    bf16x8 av[4], bv[4];
#pragma unroll
    for (int m = 0; m < 4; ++m) av[m] = *(const bf16x8*)(sA + cur * 4096 + offa[m]);
#pragma unroll
    for (int n = 0; n < 4; ++n) bv[n] = *(const bf16x8*)(sB + cur * 4096 + offb[n]);
#pragma unroll
    for (int m = 0; m < 4; ++m)
#pragma unroll
      for (int n = 0; n < 4; ++n)
        acc[m][n] = __builtin_amdgcn_mfma_f32_16x16x32_bf16(av[m], bv[n], acc[m][n], 0, 0, 0);
    asm volatile("s_waitcnt vmcnt(0)" ::: "memory");
    __syncthreads();
    cur ^= 1;
  }
}

__global__ __launch_bounds__(256) void cvt_kernel(const float* __restrict__ src,
                                                  u16* __restrict__ dst) {
  int i = blockIdx.x * 256 + threadIdx.x;   // 8 elems/thread
  float4 a = ((const float4*)src)[2 * i];
  float4 b = ((const float4*)src)[2 * i + 1];
  u16x8 o;
  o[0] = f2bf(a.x); o[1] = f2bf(a.y); o[2] = f2bf(a.z); o[3] = f2bf(a.w);
  o[4] = f2bf(b.x); o[5] = f2bf(b.y); o[6] = f2bf(b.z); o[7] = f2bf(b.w);
  ((u16x8*)dst)[i] = o;
}

__global__ __launch_bounds__(256) void transpose_cvt(const float* __restrict__ src,
                                                     u16* __restrict__ dst, int R, int C) {
  __shared__ float tle[32][33];
  int bx = blockIdx.x * 32, by = blockIdx.y * 32;
  int tx = threadIdx.x, ty = threadIdx.y;  // 32 x 8
#pragma unroll
  for (int i = 0; i < 32; i += 8) tle[ty + i][tx] = src[(size_t)(by + ty + i) * C + bx + tx];
  __syncthreads();
#pragma unroll
  for (int i = 0; i < 32; i += 8) dst[(size_t)(bx + ty + i) * R + by + tx] = f2bf(tle[tx][ty + i]);
}

__global__ __launch_bounds__(256) void proj_kernel(
    const u16* __restrict__ x, const u16* __restrict__ wqT, const u16* __restrict__ wkT,
    const u16* __restrict__ wvT, u16* __restrict__ qout, float* __restrict__ koutf,
    u16* __restrict__ kbf, float* __restrict__ voutf, u16* __restrict__ vtout) {
  __shared__ __align__(16) u16 sA[2 * 4096];
  __shared__ __align__(16) u16 sB[2 * 4096];
  const int bid = blockIdx.x;
  int mode, bm, bn;
  const u16* Bt;
  if (bid < 512) { mode = 0; bm = bid >> 4; bn = bid & 15; Bt = wqT; }
  else if (bid < 640) { mode = 1; int i = bid - 512; bm = i >> 2; bn = i & 3; Bt = wkT; }
  else { mode = 2; int i = bid - 640; bm = i >> 2; bn = i & 3; Bt = wvT; }

  f32x4 acc[4][4];
  gemm_tile(x, 2048, Bt, 2048, 2048, bm * 128, bn * 128, sA, sB, acc);

  const int t = threadIdx.x, w = t >> 6, lane = t & 63;
  const int wr = w >> 1, wc = w & 1, g = lane >> 4, r16 = lane & 15;
#pragma unroll
  for (int m = 0; m < 4; ++m)
#pragma unroll
    for (int n = 0; n < 4; ++n)
#pragma unroll
      for (int j = 0; j < 4; ++j) {
        int row = bm * 128 + wr * 64 + m * 16 + g * 4 + j;
        int col = bn * 128 + wc * 64 + n * 16 + r16;
        float v = acc[m][n][j];
        if (mode == 0) {
          qout[(size_t)row * 2048 + col] = f2bf(v * 0.125f);  // fold 1/sqrt(64)
        } else {
          int b = row >> 11, s = row & 2047;
          int h = col >> 6, d = col & 63;
          size_t idx = ((size_t)(b * 8 + h) * 2048 + s) * 64 + d;
          if (mode == 1) {
            koutf[idx] = v;              // f32 output K
            kbf[idx] = f2bf(v);          // bf16 staging copy for attention
          } else {
            voutf[idx] = v;              // f32 output V
            vtout[((size_t)(b * 8 + h) * 64 + d) * 2048 + s] = f2bf(v);  // bf16 V^T
          }
        }
      }
}

__global__ __launch_bounds__(256) void attn_kernel(
    const u16* __restrict__ Q, const u16* __restrict__ Kp,
    const u16* __restrict__ Vt, u16* __restrict__ Oh) {
  __shared__ __align__(16) u16 sK[2][4096];
  __shared__ __align__(16) u16 sV[2][4096];
  __shared__ __align__(16) u16 sP[4][2048];
  const int qb = blockIdx.x, bh = blockIdx.y;
  const int b = bh >> 5, h = bh & 31, hkv = h >> 2;
  const int t = threadIdx.x, w = t >> 6, lane = t & 63;
  const int g = lane >> 4, r16 = lane & 15;
  const int wrow0 = qb * 128 + w * 32;

  const u16* Qb = Q + (size_t)b * 2048 * 2048 + h * 64;
  bf16x8 qf[2][2];
#pragma unroll
  for (int m = 0; m < 2; ++m)
#pragma unroll
    for (int kk = 0; kk < 2; ++kk)
      qf[m][kk] = *(const bf16x8*)(Qb + (size_t)(wrow0 + m * 16 + r16) * 2048 + kk * 32 + g * 8);

  const u16* Kh = Kp + (size_t)(b * 8 + hkv) * 2048 * 64;
  const u16* Vh = Vt + (size_t)(b * 8 + hkv) * 64 * 2048;

  f32x4 accO[2][4];
  float mi[2][4], li[2][4];
#pragma unroll
  for (int m = 0; m < 2; ++m)
#pragma unroll
    for (int j = 0; j < 4; ++j) { mi[m][j] = -1e30f; li[m][j] = 0.f; }
#pragma unroll
  for (int m = 0; m < 2; ++m)
#pragma unroll
    for (int n = 0; n < 4; ++n) accO[m][n] = f32x4{0.f, 0.f, 0.f, 0.f};

  u16* sPw = sP[w];
  int offp[2][2], offkv[4][2];
#pragma unroll
  for (int m = 0; m < 2; ++m)
#pragma unroll
    for (int kk = 0; kk < 2; ++kk) offp[m][kk] = (m * 16 + r16) * 64 + (kk * 4 + g) * 8;
#pragma unroll
  for (int n = 0; n < 4; ++n)
#pragma unroll
    for (int kk = 0; kk < 2; ++kk) offkv[n][kk] = (n * 16 + r16) * 64 + (kk * 4 + g) * 8;

  const int nt = 2 * qb + 2;
  int cur = 0;
  stage64x64(Kh, 64, sK[0]);
  stage64x64(Vh, 2048, sV[0]);
  for (int it = 0; it < nt; ++it) {
    asm volatile("s_waitcnt vmcnt(0)" ::: "memory");
    __syncthreads();
    if (it + 1 < nt) {
      stage64x64(Kh + (size_t)(it + 1) * 64 * 64, 64, sK[cur ^ 1]);
      stage64x64(Vh + (it + 1) * 64, 2048, sV[cur ^ 1]);
    }
    const int kv0 = it * 64;
    if (kv0 <= wrow0 + 31) {
      f32x4 sc[2][4];
#pragma unroll
      for (int m = 0; m < 2; ++m)
#pragma unroll
        for (int n = 0; n < 4; ++n) sc[m][n] = f32x4{0.f, 0.f, 0.f, 0.f};
#pragma unroll
      for (int kk = 0; kk < 2; ++kk)
#pragma unroll
        for (int n = 0; n < 4; ++n) {
          bf16x8 kf = *(const bf16x8*)(sK[cur] + offkv[n][kk]);
#pragma unroll
          for (int m = 0; m < 2; ++m)
            sc[m][n] = __builtin_amdgcn_mfma_f32_16x16x32_bf16(qf[m][kk], kf, sc[m][n], 0, 0, 0);
        }
      if (kv0 + 63 > wrow0) {
#pragma unroll
        for (int m = 0; m < 2; ++m)
#pragma unroll
          for (int n = 0; n < 4; ++n)
#pragma unroll
            for (int j = 0; j < 4; ++j) {
              int rowg = wrow0 + m * 16 + g * 4 + j;
              int colg = kv0 + n * 16 + r16;
              if (colg > rowg) sc[m][n][j] = -1e30f;
            }
      }
#pragma unroll
      for (int m = 0; m < 2; ++m)
#pragma unroll
        for (int j = 0; j < 4; ++j) {
          float mx = fmaxf(fmaxf(sc[m][0][j], sc[m][1][j]), fmaxf(sc[m][2][j], sc[m][3][j]));
#pragma unroll
          for (int o = 1; o < 16; o <<= 1) mx = fmaxf(mx, __shfl_xor(mx, o));
          float mn = fmaxf(mi[m][j], mx);
          float scl = __expf(mi[m][j] - mn);
          float rs = 0.f;
          int row = m * 16 + g * 4 + j;
#pragma unroll
          for (int n = 0; n < 4; ++n) {
            float p = __expf(sc[m][n][j] - mn);
            rs += p;
            sPw[row * 64 + n * 16 + r16] = f2bf(p);
          }
#pragma unroll
          for (int o = 1; o < 16; o <<= 1) rs += __shfl_xor(rs, o);
          li[m][j] = li[m][j] * scl + rs;
          mi[m][j] = mn;
#pragma unroll
          for (int n = 0; n < 4; ++n) accO[m][n][j] *= scl;
        }
      asm volatile("s_waitcnt lgkmcnt(0)" ::: "memory");
#pragma unroll
      for (int kk = 0; kk < 2; ++kk) {
        bf16x8 pa[2];
#pragma unroll
        for (int m = 0; m < 2; ++m) pa[m] = *(const bf16x8*)(sPw + offp[m][kk]);
#pragma unroll
        for (int n = 0; n < 4; ++n) {
          bf16x8 vf = *(const bf16x8*)(sV[cur] + offkv[n][kk]);
#pragma unroll
          for (int m = 0; m < 2; ++m)
            accO[m][n] = __builtin_amdgcn_mfma_f32_16x16x32_bf16(pa[m], vf, accO[m][n], 0, 0, 0);
        }
      }
    }
    cur ^= 1;
  }
#pragma unroll
  for (int m = 0; m < 2; ++m)
#pragma unroll
    for (int n = 0; n < 4; ++n)
#pragma unroll
      for (int j = 0; j < 4; ++j) {
        int srow = wrow0 + m * 16 + g * 4 + j;
        int col = h * 64 + n * 16 + r16;
        Oh[((size_t)b * 2048 + srow) * 2048 + col] = f2bf(accO[m][n][j] / li[m][j]);
      }
}

__global__ __launch_bounds__(256) void outproj_kernel(const u16* __restrict__ A,
                                                      const u16* __restrict__ WoT,
                                                      float* __restrict__ out) {
  __shared__ __align__(16) u16 sA[2 * 4096];
  __shared__ __align__(16) u16 sB[2 * 4096];
  const int bm = blockIdx.x >> 4, bn = blockIdx.x & 15;
  f32x4 acc[4][4];
  gemm_tile(A, 2048, WoT, 2048, 2048, bm * 128, bn * 128, sA, sB, acc);
  const int t = threadIdx.x, w = t >> 6, lane = t & 63;
  const int wr = w >> 1, wc = w & 1, g = lane >> 4, r16 = lane & 15;
#pragma unroll
  for (int m = 0; m < 4; ++m)
#pragma unroll
    for (int n = 0; n < 4; ++n)
#pragma unroll
      for (int j = 0; j < 4; ++j) {
        int row = bm * 128 + wr * 64 + m * 16 + g * 4 + j;
        int col = bn * 128 + wc * 64 + n * 16 + r16;
        out[(size_t)row * 2048 + col] = acc[m][n][j];
      }
}

extern "C" void kernel_launch(void* const* d_in, const int* in_sizes, int n_in,
                              void* d_out, int out_size, void* d_ws, size_t ws_size,
                              hipStream_t stream) {
  const float* x  = (const float*)d_in[0];
  const float* wq = (const float*)d_in[1];
  const float* wk = (const float*)d_in[2];
  const float* wv = (const float*)d_in[3];
  const float* wo = (const float*)d_in[4];

  // ws needs 37.75 MB (proven available: round-3 guard at 40 MB did not trip).
  const size_t NEED_BYTES = 2ull * (8388608 + 4194304 + 1048576 + 1048576 + 4194304);
  if (ws_size < NEED_BYTES) return;  // signature if tripped: error == 3.546875

  // d_out (f32): [ out 8.4M | K 2.1M | V 2.1M ]
  float* outf  = (float*)d_out;
  float* koutf = outf + (size_t)8388608;
  float* voutf = koutf + (size_t)2097152;

  // bf16 intermediates parked in the out-region (33.5 MB; overwritten by outproj last):
  // Qs [0,16.8M) | Vt [16.8,21M) | Kbf [21,25.2M)  (byte ranges)
  u16* Qs  = (u16*)d_out;
  u16* Vt  = Qs + (size_t)8388608;
  u16* Kbf = Vt + (size_t)2097152;

  u16* ws   = (u16*)d_ws;
  u16* xbf  = ws;                                       // dead after proj -> reused as Oh
  u16* Oh   = ws;
  u16* wqT  = ws  + (size_t)8388608;                    // 2048x2048
  u16* wkT  = wqT + (size_t)4194304;                    // 512x2048
  u16* wvT  = wkT + (size_t)1048576;                    // 512x2048
  u16* woT  = wvT + (size_t)1048576;                    // 2048x2048

  dim3 tb(32, 8);
  cvt_kernel<<<4096, 256, 0, stream>>>(x, xbf);
  transpose_cvt<<<dim3(64, 64), tb, 0, stream>>>(wq, wqT, 2048, 2048);
  transpose_cvt<<<dim3(16, 64), tb, 0, stream>>>(wk, wkT, 2048, 512);
  transpose_cvt<<<dim3(16, 64), tb, 0, stream>>>(wv, wvT, 2048, 512);
  transpose_cvt<<<dim3(64, 64), tb, 0, stream>>>(wo, woT, 2048, 2048);

  proj_kernel<<<768, 256, 0, stream>>>(xbf, wqT, wkT, wvT, Qs, koutf, Kbf, voutf, Vt);
  attn_kernel<<<dim3(16, 64), 256, 0, stream>>>(Qs, Kbf, Vt, Oh);
  outproj_kernel<<<512, 256, 0, stream>>>(Oh, woT, outf);
}

// Round 5
// 356.203 us; speedup vs baseline: 1.1400x; 1.1400x over previous
//
#include <hip/hip_runtime.h>

typedef unsigned short u16;
typedef __attribute__((ext_vector_type(8))) __bf16 bf16x8;
typedef __attribute__((ext_vector_type(8))) u16 u16x8;
typedef __attribute__((ext_vector_type(4))) float f32x4;

#define DEVI static __device__ __forceinline__

// B=2, S=2048, D=2048, HQ=32, HKV=8, HD=64, G=4, KV_DIM=512, M=B*S=4096
// Device inputs: f32 (+ int32 mask, unused). Device outputs: f32 (out,K,V concat).
// bf16 internals (MFMA) under the bf16 tolerance policy.

DEVI u16 f2bf(float f) {
  unsigned u = __float_as_uint(f);
  u += 0x7fff + ((u >> 16) & 1);   // RNE
  return (u16)(u >> 16);
}

DEVI void gll16(const void* g, void* l) {
  __builtin_amdgcn_global_load_lds((const __attribute__((address_space(1))) void*)g,
                                   (__attribute__((address_space(3))) void*)l, 16, 0, 0);
}

// Stage 128x32 bf16 tile, XOR-swizzled via source (round-2 scheme, proven r2==r3):
// LDS slot c holds logical chunk (c&3)^(row&3) of row c>>2.
DEVI void stage128x32(const u16* g, int ld, u16* lds) {
  int t = threadIdx.x, w = t >> 6, l = t & 63;
#pragma unroll
  for (int r = 0; r < 2; ++r) {
    int c = (w * 2 + r) * 64 + l;
    int row = c >> 2;
    int p = (c & 3) ^ (row & 3);
    gll16(g + (size_t)row * ld + p * 8, (char*)lds + (w * 2 + r) * 1024);
  }
}

// Stage 64x64 bf16 tile, XOR-swizzled: slot c holds logical chunk (c&7)^(row&7) of row c>>3.
DEVI void stage64x64(const u16* g, int ld, u16* lds) {
  int t = threadIdx.x, w = t >> 6, l = t & 63;
#pragma unroll
  for (int r = 0; r < 2; ++r) {
    int c = (w * 2 + r) * 64 + l;
    int row = c >> 3;
    int p = (c & 7) ^ (row & 7);
    gll16(g + (size_t)row * ld + p * 8, (char*)lds + (w * 2 + r) * 1024);
  }
}

// 128x128 tile GEMM: C = A[m0:,:K] * Bt[n0:,:K]^T. 4 waves 2x2, each 64x64 (4x4 frags).
DEVI void gemm_tile(const u16* A, int lda, const u16* Bt, int ldb, int K,
                    int m0, int n0, u16* sA, u16* sB, f32x4 acc[4][4]) {
  const int t = threadIdx.x, w = t >> 6, lane = t & 63;
  const int wr = w >> 1, wc = w & 1, g = lane >> 4, r16 = lane & 15;
  int offa[4], offb[4];
#pragma unroll
  for (int m = 0; m < 4; ++m) {
    int row = wr * 64 + m * 16 + r16;
    offa[m] = row * 32 + ((g ^ (row & 3)) << 3);
  }
#pragma unroll
  for (int n = 0; n < 4; ++n) {
    int row = wc * 64 + n * 16 + r16;
    offb[n] = row * 32 + ((g ^ (row & 3)) << 3);
  }
#pragma unroll
  for (int m = 0; m < 4; ++m)
#pragma unroll
    for (int n = 0; n < 4; ++n) acc[m][n] = f32x4{0.f, 0.f, 0.f, 0.f};

  const u16* At = A + (size_t)m0 * lda;
  const u16* Bb = Bt + (size_t)n0 * ldb;
  stage128x32(At, lda, sA);
  stage128x32(Bb, ldb, sB);
  asm volatile("s_waitcnt vmcnt(0)" ::: "memory");
  __syncthreads();
  const int nk = K >> 5;
  int cur = 0;
  for (int kt = 0; kt < nk; ++kt) {
    if (kt + 1 < nk) {
      stage128x32(At + (kt + 1) * 32, lda, sA + (cur ^ 1) * 4096);
      stage128x32(Bb + (kt + 1) * 32, ldb, sB + (cur ^ 1) * 4096);
    }
    bf16x8 av[4], bv[4];
#pragma unroll
    for (int m = 0; m < 4; ++m) av[m] = *(const bf16x8*)(sA + cur * 4096 + offa[m]);
#pragma unroll
    for (int n = 0; n < 4; ++n) bv[n] = *(const bf16x8*)(sB + cur * 4096 + offb[n]);
#pragma unroll
    for (int m = 0; m < 4; ++m)
#pragma unroll
      for (int n = 0; n < 4; ++n)
        acc[m][n] = __builtin_amdgcn_mfma_f32_16x16x32_bf16(av[m], bv[n], acc[m][n], 0, 0, 0);
    asm volatile("s_waitcnt vmcnt(0)" ::: "memory");
    __syncthreads();
    cur ^= 1;
  }
}

__global__ __launch_bounds__(256) void cvt_kernel(const float* __restrict__ src,
                                                  u16* __restrict__ dst) {
  int i = blockIdx.x * 256 + threadIdx.x;   // 8 elems/thread
  float4 a = ((const float4*)src)[2 * i];
  float4 b = ((const float4*)src)[2 * i + 1];
  u16x8 o;
  o[0] = f2bf(a.x); o[1] = f2bf(a.y); o[2] = f2bf(a.z); o[3] = f2bf(a.w);
  o[4] = f2bf(b.x); o[5] = f2bf(b.y); o[6] = f2bf(b.z); o[7] = f2bf(b.w);
  ((u16x8*)dst)[i] = o;
}

__global__ __launch_bounds__(256) void transpose_cvt(const float* __restrict__ src,
                                                     u16* __restrict__ dst, int R, int C) {
  __shared__ float tle[32][33];
  int bx = blockIdx.x * 32, by = blockIdx.y * 32;
  int tx = threadIdx.x, ty = threadIdx.y;  // 32 x 8
#pragma unroll
  for (int i = 0; i < 32; i += 8) tle[ty + i][tx] = src[(size_t)(by + ty + i) * C + bx + tx];
  __syncthreads();
#pragma unroll
  for (int i = 0; i < 32; i += 8) dst[(size_t)(bx + ty + i) * R + by + tx] = f2bf(tle[tx][ty + i]);
}

__global__ __launch_bounds__(256) void proj_kernel(
    const u16* __restrict__ x, const u16* __restrict__ wqT, const u16* __restrict__ wkT,
    const u16* __restrict__ wvT, u16* __restrict__ qout, float* __restrict__ koutf,
    u16* __restrict__ kbf, float* __restrict__ voutf, u16* __restrict__ vtout) {
  __shared__ __align__(16) u16 sA[2 * 4096];
  __shared__ __align__(16) u16 sB[2 * 4096];
  const int bid = blockIdx.x;
  int mode, bm, bn;
  const u16* Bt;
  if (bid < 512) { mode = 0; bm = bid >> 4; bn = bid & 15; Bt = wqT; }
  else if (bid < 640) { mode = 1; int i = bid - 512; bm = i >> 2; bn = i & 3; Bt = wkT; }
  else { mode = 2; int i = bid - 640; bm = i >> 2; bn = i & 3; Bt = wvT; }

  f32x4 acc[4][4];
  gemm_tile(x, 2048, Bt, 2048, 2048, bm * 128, bn * 128, sA, sB, acc);

  const int t = threadIdx.x, w = t >> 6, lane = t & 63;
  const int wr = w >> 1, wc = w & 1, g = lane >> 4, r16 = lane & 15;
#pragma unroll
  for (int m = 0; m < 4; ++m)
#pragma unroll
    for (int n = 0; n < 4; ++n)
#pragma unroll
      for (int j = 0; j < 4; ++j) {
        int row = bm * 128 + wr * 64 + m * 16 + g * 4 + j;
        int col = bn * 128 + wc * 64 + n * 16 + r16;
        float v = acc[m][n][j];
        if (mode == 0) {
          qout[(size_t)row * 2048 + col] = f2bf(v * 0.125f);  // fold 1/sqrt(64)
        } else {
          int b = row >> 11, s = row & 2047;
          int h = col >> 6, d = col & 63;
          size_t idx = ((size_t)(b * 8 + h) * 2048 + s) * 64 + d;
          if (mode == 1) {
            koutf[idx] = v;
            kbf[idx] = f2bf(v);
          } else {
            voutf[idx] = v;
            vtout[((size_t)(b * 8 + h) * 64 + d) * 2048 + s] = f2bf(v);
          }
        }
      }
}

// One 32-row-wave x 64-col KV tile of flash attention for one q-tile state.
DEVI void attn_tile(const u16* sKc, const u16* sVc, u16* sPw,
                    const bf16x8 (&qf)[2][2], f32x4 (&accO)[2][4],
                    float (&mi)[2][4], float (&li)[2][4],
                    int wrow0, int kv0, int g, int r16,
                    const int (&offp)[2][2], const int (&offkv)[4][2]) {
  if (kv0 > wrow0 + 31) return;
  f32x4 sc[2][4];
#pragma unroll
  for (int m = 0; m < 2; ++m)
#pragma unroll
    for (int n = 0; n < 4; ++n) sc[m][n] = f32x4{0.f, 0.f, 0.f, 0.f};
#pragma unroll
  for (int kk = 0; kk < 2; ++kk)
#pragma unroll
    for (int n = 0; n < 4; ++n) {
      bf16x8 kf = *(const bf16x8*)(sKc + offkv[n][kk]);
#pragma unroll
      for (int m = 0; m < 2; ++m)
        sc[m][n] = __builtin_amdgcn_mfma_f32_16x16x32_bf16(qf[m][kk], kf, sc[m][n], 0, 0, 0);
    }
  if (kv0 + 63 > wrow0) {  // diagonal: causal mask
#pragma unroll
    for (int m = 0; m < 2; ++m)
#pragma unroll
      for (int n = 0; n < 4; ++n)
#pragma unroll
        for (int j = 0; j < 4; ++j) {
          int rowg = wrow0 + m * 16 + g * 4 + j;
          int colg = kv0 + n * 16 + r16;
          if (colg > rowg) sc[m][n][j] = -1e30f;
        }
  }
#pragma unroll
  for (int m = 0; m < 2; ++m)
#pragma unroll
    for (int j = 0; j < 4; ++j) {
      float mx = fmaxf(fmaxf(sc[m][0][j], sc[m][1][j]), fmaxf(sc[m][2][j], sc[m][3][j]));
#pragma unroll
      for (int o = 1; o < 16; o <<= 1) mx = fmaxf(mx, __shfl_xor(mx, o));
      float mn = fmaxf(mi[m][j], mx);
      float scl = __expf(mi[m][j] - mn);
      float rs = 0.f;
      int row = m * 16 + g * 4 + j;
#pragma unroll
      for (int n = 0; n < 4; ++n) {
        float p = __expf(sc[m][n][j] - mn);
        rs += p;
        int col = n * 16 + r16;
        sPw[row * 64 + (((col >> 3) ^ (row & 7)) << 3) + (col & 7)] = f2bf(p);
      }
#pragma unroll
      for (int o = 1; o < 16; o <<= 1) rs += __shfl_xor(rs, o);
      li[m][j] = li[m][j] * scl + rs;
      mi[m][j] = mn;
#pragma unroll
      for (int n = 0; n < 4; ++n) accO[m][n][j] *= scl;
    }
  asm volatile("s_waitcnt lgkmcnt(0)" ::: "memory");
#pragma unroll
  for (int kk = 0; kk < 2; ++kk) {
    bf16x8 pa[2];
#pragma unroll
    for (int m = 0; m < 2; ++m) pa[m] = *(const bf16x8*)(sPw + offp[m][kk]);
#pragma unroll
    for (int n = 0; n < 4; ++n) {
      bf16x8 vf = *(const bf16x8*)(sVc + offkv[n][kk]);
#pragma unroll
      for (int m = 0; m < 2; ++m)
        accO[m][n] = __builtin_amdgcn_mfma_f32_16x16x32_bf16(pa[m], vf, accO[m][n], 0, 0, 0);
    }
  }
}

// Balanced causal pairing: block bx handles q-tiles qhi=15-bx and qlo=bx (34 tile-steps each).
__global__ __launch_bounds__(256) void attn_kernel(
    const u16* __restrict__ Q, const u16* __restrict__ Kp,
    const u16* __restrict__ Vt, u16* __restrict__ Oh) {
  __shared__ __align__(16) u16 sK[2][4096];
  __shared__ __align__(16) u16 sV[2][4096];
  __shared__ __align__(16) u16 sP[4][2048];
  const int bx = blockIdx.x, bh = blockIdx.y;
  const int qhi = 15 - bx, qlo = bx;
  const int b = bh >> 5, h = bh & 31, hkv = h >> 2;
  const int t = threadIdx.x, w = t >> 6, lane = t & 63;
  const int g = lane >> 4, r16 = lane & 15;
  const int wrow_hi = qhi * 128 + w * 32;
  const int wrow_lo = qlo * 128 + w * 32;

  const u16* Qb = Q + (size_t)b * 2048 * 2048 + h * 64;
  bf16x8 qfh[2][2], qfl[2][2];
#pragma unroll
  for (int m = 0; m < 2; ++m)
#pragma unroll
    for (int kk = 0; kk < 2; ++kk) {
      qfh[m][kk] = *(const bf16x8*)(Qb + (size_t)(wrow_hi + m * 16 + r16) * 2048 + kk * 32 + g * 8);
      qfl[m][kk] = *(const bf16x8*)(Qb + (size_t)(wrow_lo + m * 16 + r16) * 2048 + kk * 32 + g * 8);
    }

  const u16* Kh = Kp + (size_t)(b * 8 + hkv) * 2048 * 64;
  const u16* Vh = Vt + (size_t)(b * 8 + hkv) * 64 * 2048;

  f32x4 accOh[2][4], accOl[2][4];
  float mih[2][4], lih[2][4], mil[2][4], lil[2][4];
#pragma unroll
  for (int m = 0; m < 2; ++m)
#pragma unroll
    for (int j = 0; j < 4; ++j) {
      mih[m][j] = -1e30f; lih[m][j] = 0.f;
      mil[m][j] = -1e30f; lil[m][j] = 0.f;
    }
#pragma unroll
  for (int m = 0; m < 2; ++m)
#pragma unroll
    for (int n = 0; n < 4; ++n) { accOh[m][n] = f32x4{0,0,0,0}; accOl[m][n] = f32x4{0,0,0,0}; }

  u16* sPw = sP[w];
  int offp[2][2], offkv[4][2];
#pragma unroll
  for (int m = 0; m < 2; ++m)
#pragma unroll
    for (int kk = 0; kk < 2; ++kk) {
      int row = m * 16 + r16;
      offp[m][kk] = row * 64 + (((kk * 4 + g) ^ (row & 7)) << 3);
    }
#pragma unroll
  for (int n = 0; n < 4; ++n)
#pragma unroll
    for (int kk = 0; kk < 2; ++kk) {
      int row = n * 16 + r16;
      offkv[n][kk] = row * 64 + (((kk * 4 + g) ^ (row & 7)) << 3);
    }

  const int nt_hi = 2 * qhi + 2, nt_lo = 2 * qlo + 2;
  int cur = 0;
  stage64x64(Kh, 64, sK[0]);
  stage64x64(Vh, 2048, sV[0]);
  for (int it = 0; it < nt_hi; ++it) {
    asm volatile("s_waitcnt vmcnt(0)" ::: "memory");
    __syncthreads();
    if (it + 1 < nt_hi) {
      stage64x64(Kh + (size_t)(it + 1) * 64 * 64, 64, sK[cur ^ 1]);
      stage64x64(Vh + (it + 1) * 64, 2048, sV[cur ^ 1]);
    }
    const int kv0 = it * 64;
    attn_tile(sK[cur], sV[cur], sPw, qfh, accOh, mih, lih, wrow_hi, kv0, g, r16, offp, offkv);
    if (it < nt_lo)
      attn_tile(sK[cur], sV[cur], sPw, qfl, accOl, mil, lil, wrow_lo, kv0, g, r16, offp, offkv);
    cur ^= 1;
  }
#pragma unroll
  for (int m = 0; m < 2; ++m)
#pragma unroll
    for (int n = 0; n < 4; ++n)
#pragma unroll
      for (int j = 0; j < 4; ++j) {
        int col = h * 64 + n * 16 + r16;
        int rh = wrow_hi + m * 16 + g * 4 + j;
        int rl = wrow_lo + m * 16 + g * 4 + j;
        Oh[((size_t)b * 2048 + rh) * 2048 + col] = f2bf(accOh[m][n][j] / lih[m][j]);
        Oh[((size_t)b * 2048 + rl) * 2048 + col] = f2bf(accOl[m][n][j] / lil[m][j]);
      }
}

__global__ __launch_bounds__(256) void outproj_kernel(const u16* __restrict__ A,
                                                      const u16* __restrict__ WoT,
                                                      float* __restrict__ out) {
  __shared__ __align__(16) u16 sA[2 * 4096];
  __shared__ __align__(16) u16 sB[2 * 4096];
  const int bm = blockIdx.x >> 4, bn = blockIdx.x & 15;
  f32x4 acc[4][4];
  gemm_tile(A, 2048, WoT, 2048, 2048, bm * 128, bn * 128, sA, sB, acc);
  const int t = threadIdx.x, w = t >> 6, lane = t & 63;
  const int wr = w >> 1, wc = w & 1, g = lane >> 4, r16 = lane & 15;
#pragma unroll
  for (int m = 0; m < 4; ++m)
#pragma unroll
    for (int n = 0; n < 4; ++n)
#pragma unroll
      for (int j = 0; j < 4; ++j) {
        int row = bm * 128 + wr * 64 + m * 16 + g * 4 + j;
        int col = bn * 128 + wc * 64 + n * 16 + r16;
        out[(size_t)row * 2048 + col] = acc[m][n][j];
      }
}

extern "C" void kernel_launch(void* const* d_in, const int* in_sizes, int n_in,
                              void* d_out, int out_size, void* d_ws, size_t ws_size,
                              hipStream_t stream) {
  const float* x  = (const float*)d_in[0];
  const float* wq = (const float*)d_in[1];
  const float* wk = (const float*)d_in[2];
  const float* wv = (const float*)d_in[3];
  const float* wo = (const float*)d_in[4];

  const size_t NEED_BYTES = 2ull * (8388608 + 4194304 + 1048576 + 1048576 + 4194304);
  if (ws_size < NEED_BYTES) return;

  // d_out (f32): [ out 8.4M | K 2.1M | V 2.1M ] elements
  float* outf  = (float*)d_out;
  float* koutf = outf + (size_t)8388608;
  float* voutf = koutf + (size_t)2097152;

  // bf16 intermediates parked in the out-region (overwritten by outproj last):
  u16* Qs  = (u16*)d_out;                 // (B,S,D) scaled Q
  u16* Vt  = Qs + (size_t)8388608;        // (B,HKV,HD,S)
  u16* Kbf = Vt + (size_t)2097152;        // (B,HKV,S,HD)

  u16* ws   = (u16*)d_ws;
  u16* xbf  = ws;                         // dead after proj -> reused as Oh
  u16* Oh   = ws;
  u16* wqT  = ws  + (size_t)8388608;      // 2048x2048
  u16* wkT  = wqT + (size_t)4194304;      // 512x2048
  u16* wvT  = wkT + (size_t)1048576;      // 512x2048
  u16* woT  = wvT + (size_t)1048576;      // 2048x2048

  dim3 tb(32, 8);
  cvt_kernel<<<4096, 256, 0, stream>>>(x, xbf);
  transpose_cvt<<<dim3(64, 64), tb, 0, stream>>>(wq, wqT, 2048, 2048);
  transpose_cvt<<<dim3(16, 64), tb, 0, stream>>>(wk, wkT, 2048, 512);
  transpose_cvt<<<dim3(16, 64), tb, 0, stream>>>(wv, wvT, 2048, 512);
  transpose_cvt<<<dim3(64, 64), tb, 0, stream>>>(wo, woT, 2048, 2048);

  proj_kernel<<<768, 256, 0, stream>>>(xbf, wqT, wkT, wvT, Qs, koutf, Kbf, voutf, Vt);
  attn_kernel<<<dim3(8, 64), 256, 0, stream>>>(Qs, Kbf, Vt, Oh);
  outproj_kernel<<<512, 256, 0, stream>>>(Oh, woT, outf);
}

// Round 6
// 315.812 us; speedup vs baseline: 1.2858x; 1.1279x over previous
//
#include <hip/hip_runtime.h>

typedef unsigned short u16;
typedef unsigned int u32;
typedef __attribute__((ext_vector_type(8))) __bf16 bf16x8;
typedef __attribute__((ext_vector_type(8))) u16 u16x8;
typedef __attribute__((ext_vector_type(2))) u32 u32x2;
typedef __attribute__((ext_vector_type(4))) float f32x4;

#define DEVI static __device__ __forceinline__

// B=2, S=2048, D=2048, HQ=32, HKV=8, HD=64, G=4, KV_DIM=512, M=B*S=4096
// Inputs f32 (+int32 mask unused). Outputs f32 (out,K,V concat). bf16 internals.

DEVI u16 f2bf(float f) {
  unsigned u = __float_as_uint(f);
  u += 0x7fff + ((u >> 16) & 1);   // RNE
  return (u16)(u >> 16);
}

DEVI u32 cvt_pk_bf16(float lo, float hi) {
  u32 r;
  asm("v_cvt_pk_bf16_f32 %0, %1, %2" : "=v"(r) : "v"(lo), "v"(hi));
  return r;
}

DEVI float bperm_f(int srclane, float v) {
  return __int_as_float(__builtin_amdgcn_ds_bpermute(srclane << 2, __float_as_int(v)));
}

DEVI void gll16(const void* g, void* l) {
  __builtin_amdgcn_global_load_lds((const __attribute__((address_space(1))) void*)g,
                                   (__attribute__((address_space(3))) void*)l, 16, 0, 0);
}

// Stage 128x32 bf16 tile, XOR-swizzled via source.
DEVI void stage128x32(const u16* g, int ld, u16* lds) {
  int t = threadIdx.x, w = t >> 6, l = t & 63;
#pragma unroll
  for (int r = 0; r < 2; ++r) {
    int c = (w * 2 + r) * 64 + l;
    int row = c >> 2;
    int p = (c & 3) ^ (row & 3);
    gll16(g + (size_t)row * ld + p * 8, (char*)lds + (w * 2 + r) * 1024);
  }
}

// Stage 64x64 bf16 tile, XOR-swizzled.
DEVI void stage64x64(const u16* g, int ld, u16* lds) {
  int t = threadIdx.x, w = t >> 6, l = t & 63;
#pragma unroll
  for (int r = 0; r < 2; ++r) {
    int c = (w * 2 + r) * 64 + l;
    int row = c >> 3;
    int p = (c & 7) ^ (row & 7);
    gll16(g + (size_t)row * ld + p * 8, (char*)lds + (w * 2 + r) * 1024);
  }
}

// 128x128 tile GEMM (unchanged from round 5, passing).
DEVI void gemm_tile(const u16* A, int lda, const u16* Bt, int ldb, int K,
                    int m0, int n0, u16* sA, u16* sB, f32x4 acc[4][4]) {
  const int t = threadIdx.x, w = t >> 6, lane = t & 63;
  const int wr = w >> 1, wc = w & 1, g = lane >> 4, r16 = lane & 15;
  int offa[4], offb[4];
#pragma unroll
  for (int m = 0; m < 4; ++m) {
    int row = wr * 64 + m * 16 + r16;
    offa[m] = row * 32 + ((g ^ (row & 3)) << 3);
  }
#pragma unroll
  for (int n = 0; n < 4; ++n) {
    int row = wc * 64 + n * 16 + r16;
    offb[n] = row * 32 + ((g ^ (row & 3)) << 3);
  }
#pragma unroll
  for (int m = 0; m < 4; ++m)
#pragma unroll
    for (int n = 0; n < 4; ++n) acc[m][n] = f32x4{0.f, 0.f, 0.f, 0.f};

  const u16* At = A + (size_t)m0 * lda;
  const u16* Bb = Bt + (size_t)n0 * ldb;
  stage128x32(At, lda, sA);
  stage128x32(Bb, ldb, sB);
  asm volatile("s_waitcnt vmcnt(0)" ::: "memory");
  __syncthreads();
  const int nk = K >> 5;
  int cur = 0;
  for (int kt = 0; kt < nk; ++kt) {
    if (kt + 1 < nk) {
      stage128x32(At + (kt + 1) * 32, lda, sA + (cur ^ 1) * 4096);
      stage128x32(Bb + (kt + 1) * 32, ldb, sB + (cur ^ 1) * 4096);
    }
    bf16x8 av[4], bv[4];
#pragma unroll
    for (int m = 0; m < 4; ++m) av[m] = *(const bf16x8*)(sA + cur * 4096 + offa[m]);
#pragma unroll
    for (int n = 0; n < 4; ++n) bv[n] = *(const bf16x8*)(sB + cur * 4096 + offb[n]);
#pragma unroll
    for (int m = 0; m < 4; ++m)
#pragma unroll
      for (int n = 0; n < 4; ++n)
        acc[m][n] = __builtin_amdgcn_mfma_f32_16x16x32_bf16(av[m], bv[n], acc[m][n], 0, 0, 0);
    asm volatile("s_waitcnt vmcnt(0)" ::: "memory");
    __syncthreads();
    cur ^= 1;
  }
}

__global__ __launch_bounds__(256) void cvt_kernel(const float* __restrict__ src,
                                                  u16* __restrict__ dst) {
  int i = blockIdx.x * 256 + threadIdx.x;
  float4 a = ((const float4*)src)[2 * i];
  float4 b = ((const float4*)src)[2 * i + 1];
  u16x8 o;
  o[0] = f2bf(a.x); o[1] = f2bf(a.y); o[2] = f2bf(a.z); o[3] = f2bf(a.w);
  o[4] = f2bf(b.x); o[5] = f2bf(b.y); o[6] = f2bf(b.z); o[7] = f2bf(b.w);
  ((u16x8*)dst)[i] = o;
}

// All four weight transposes fused in one launch. Source rows R=2048 always.
__global__ __launch_bounds__(256) void transpose_all(
    const float* __restrict__ wq, const float* __restrict__ wk,
    const float* __restrict__ wv, const float* __restrict__ wo,
    u16* __restrict__ wqT, u16* __restrict__ wkT,
    u16* __restrict__ wvT, u16* __restrict__ woT) {
  __shared__ float tle[32][33];
  int bxr = blockIdx.x;
  const float* src; u16* dst; int C, bxl;
  if (bxr < 64)       { src = wq; dst = wqT; C = 2048; bxl = bxr; }
  else if (bxr < 80)  { src = wk; dst = wkT; C = 512;  bxl = bxr - 64; }
  else if (bxr < 96)  { src = wv; dst = wvT; C = 512;  bxl = bxr - 80; }
  else                { src = wo; dst = woT; C = 2048; bxl = bxr - 96; }
  int bx = bxl * 32, by = blockIdx.y * 32;
  int tx = threadIdx.x, ty = threadIdx.y;  // 32 x 8
#pragma unroll
  for (int i = 0; i < 32; i += 8) tle[ty + i][tx] = src[(size_t)(by + ty + i) * C + bx + tx];
  __syncthreads();
#pragma unroll
  for (int i = 0; i < 32; i += 8)
    dst[(size_t)(bx + ty + i) * 2048 + by + tx] = f2bf(tle[tx][ty + i]);
}

__global__ __launch_bounds__(256) void proj_kernel(
    const u16* __restrict__ x, const u16* __restrict__ wqT, const u16* __restrict__ wkT,
    const u16* __restrict__ wvT, u16* __restrict__ qout, float* __restrict__ koutf,
    u16* __restrict__ kbf, float* __restrict__ voutf, u16* __restrict__ vtout) {
  __shared__ __align__(16) u16 sA[2 * 4096];
  __shared__ __align__(16) u16 sB[2 * 4096];
  const int bid = blockIdx.x;
  int mode, bm, bn;
  const u16* Bt;
  if (bid < 512) { mode = 0; bm = bid >> 4; bn = bid & 15; Bt = wqT; }
  else if (bid < 640) { mode = 1; int i = bid - 512; bm = i >> 2; bn = i & 3; Bt = wkT; }
  else { mode = 2; int i = bid - 640; bm = i >> 2; bn = i & 3; Bt = wvT; }

  f32x4 acc[4][4];
  gemm_tile(x, 2048, Bt, 2048, 2048, bm * 128, bn * 128, sA, sB, acc);

  const int t = threadIdx.x, w = t >> 6, lane = t & 63;
  const int wr = w >> 1, wc = w & 1, g = lane >> 4, r16 = lane & 15;
  // fold 1/sqrt(64) and log2(e) into Q so softmax can use exp2
  const float QSCALE = 0.125f * 1.44269504088896340736f;
#pragma unroll
  for (int m = 0; m < 4; ++m)
#pragma unroll
    for (int n = 0; n < 4; ++n)
#pragma unroll
      for (int j = 0; j < 4; ++j) {
        int row = bm * 128 + wr * 64 + m * 16 + g * 4 + j;
        int col = bn * 128 + wc * 64 + n * 16 + r16;
        float v = acc[m][n][j];
        if (mode == 0) {
          qout[(size_t)row * 2048 + col] = f2bf(v * QSCALE);
        } else {
          int b = row >> 11, s = row & 2047;
          int h = col >> 6, d = col & 63;
          size_t idx = ((size_t)(b * 8 + h) * 2048 + s) * 64 + d;
          if (mode == 1) {
            koutf[idx] = v;
            kbf[idx] = f2bf(v);
          } else {
            voutf[idx] = v;
            vtout[((size_t)(b * 8 + h) * 64 + d) * 2048 + s] = f2bf(v);
          }
        }
      }
}

// One 32-q-row x 64-kv tile step, SWAPPED QK^T: S^T = mfma(K_frag, Q_frag).
// Lane owns q = m*16+r16; its 16 scores (n,j) are in-lane -> row reduce is
// 15 VALU + 2 shuffles. P packed via cvt_pk and stored as ds_write_b64.
DEVI void attn_tile(const u16* sKc, const u16* sVc, u16* sPw,
                    const bf16x8 (&qf)[2][2], f32x4 (&accO)[2][4],
                    float (&mi)[2], float (&li)[2],
                    int wrow0, int kv0, int lane, int g, int r16,
                    const int (&offp)[2][2], const int (&offkv)[4][2]) {
  if (kv0 > wrow0 + 31) return;
  f32x4 st[2][4];
#pragma unroll
  for (int m = 0; m < 2; ++m)
#pragma unroll
    for (int n = 0; n < 4; ++n) st[m][n] = f32x4{0.f, 0.f, 0.f, 0.f};
#pragma unroll
  for (int kk = 0; kk < 2; ++kk)
#pragma unroll
    for (int n = 0; n < 4; ++n) {
      bf16x8 kf = *(const bf16x8*)(sKc + offkv[n][kk]);
#pragma unroll
      for (int m = 0; m < 2; ++m)
        st[m][n] = __builtin_amdgcn_mfma_f32_16x16x32_bf16(kf, qf[m][kk], st[m][n], 0, 0, 0);
    }
  if (kv0 + 63 > wrow0) {  // diagonal: causal mask. kv = kv0+n*16+g*4+j, q = wrow0+m*16+r16
#pragma unroll
    for (int m = 0; m < 2; ++m) {
      int qg = wrow0 + m * 16 + r16;
#pragma unroll
      for (int n = 0; n < 4; ++n)
#pragma unroll
        for (int j = 0; j < 4; ++j) {
          int kvg = kv0 + n * 16 + g * 4 + j;
          if (kvg > qg) st[m][n][j] = -1e30f;
        }
    }
  }
#pragma unroll
  for (int m = 0; m < 2; ++m) {
    // in-lane tree max over 16 values
    float a0 = fmaxf(fmaxf(st[m][0][0], st[m][0][1]), fmaxf(st[m][0][2], st[m][0][3]));
    float a1 = fmaxf(fmaxf(st[m][1][0], st[m][1][1]), fmaxf(st[m][1][2], st[m][1][3]));
    float a2 = fmaxf(fmaxf(st[m][2][0], st[m][2][1]), fmaxf(st[m][2][2], st[m][2][3]));
    float a3 = fmaxf(fmaxf(st[m][3][0], st[m][3][1]), fmaxf(st[m][3][2], st[m][3][3]));
    float pmax = fmaxf(fmaxf(a0, a1), fmaxf(a2, a3));
    pmax = fmaxf(pmax, __shfl_xor(pmax, 16));  // combine g-groups; r16 preserved
    pmax = fmaxf(pmax, __shfl_xor(pmax, 32));
    float mn = fmaxf(mi[m], pmax);
    float scl = exp2f(mi[m] - mn);
    mi[m] = mn;
    float rs = 0.f;
    u32 pk[4][2];
#pragma unroll
    for (int n = 0; n < 4; ++n) {
      float p0 = exp2f(st[m][n][0] - mn);
      float p1 = exp2f(st[m][n][1] - mn);
      float p2 = exp2f(st[m][n][2] - mn);
      float p3 = exp2f(st[m][n][3] - mn);
      rs += (p0 + p1) + (p2 + p3);
      pk[n][0] = cvt_pk_bf16(p0, p1);
      pk[n][1] = cvt_pk_bf16(p2, p3);
    }
    rs += __shfl_xor(rs, 16);
    rs += __shfl_xor(rs, 32);
    li[m] = li[m] * scl + rs;
    // store P row q=m*16+r16: kv chunk = n*2+(g>>1), half (g&1), XOR-swizzled by row
    int row = m * 16 + r16;
    u16* pbase = sPw + row * 64 + (g & 1) * 4;
#pragma unroll
    for (int n = 0; n < 4; ++n) {
      u32x2 wv2 = {pk[n][0], pk[n][1]};
      *(u32x2*)(pbase + (((n * 2 + (g >> 1)) ^ (row & 7)) << 3)) = wv2;
    }
    // rescale accO: its rows are q = m*16+g*4+j -> broadcast scl from lane r16=g*4+j
#pragma unroll
    for (int j = 0; j < 4; ++j) {
      float sj = bperm_f((lane & 48) | (((lane >> 4) & 3) * 4 + j), scl);
#pragma unroll
      for (int n = 0; n < 4; ++n) accO[m][n][j] *= sj;
    }
  }
  asm volatile("s_waitcnt lgkmcnt(0)" ::: "memory");
#pragma unroll
  for (int kk = 0; kk < 2; ++kk) {
    bf16x8 pa[2];
#pragma unroll
    for (int m = 0; m < 2; ++m) pa[m] = *(const bf16x8*)(sPw + offp[m][kk]);
#pragma unroll
    for (int n = 0; n < 4; ++n) {
      bf16x8 vf = *(const bf16x8*)(sVc + offkv[n][kk]);
#pragma unroll
      for (int m = 0; m < 2; ++m)
        accO[m][n] = __builtin_amdgcn_mfma_f32_16x16x32_bf16(pa[m], vf, accO[m][n], 0, 0, 0);
    }
  }
}

// Balanced causal pairing: block bx handles q-tiles qhi=15-bx and qlo=bx.
__global__ __launch_bounds__(256) void attn_kernel(
    const u16* __restrict__ Q, const u16* __restrict__ Kp,
    const u16* __restrict__ Vt, u16* __restrict__ Oh) {
  __shared__ __align__(16) u16 sK[2][4096];
  __shared__ __align__(16) u16 sV[2][4096];
  __shared__ __align__(16) u16 sP[4][2048];
  const int bx = blockIdx.x, bh = blockIdx.y;
  const int qhi = 15 - bx, qlo = bx;
  const int b = bh >> 5, h = bh & 31, hkv = h >> 2;
  const int t = threadIdx.x, w = t >> 6, lane = t & 63;
  const int g = lane >> 4, r16 = lane & 15;
  const int wrow_hi = qhi * 128 + w * 32;
  const int wrow_lo = qlo * 128 + w * 32;

  const u16* Qb = Q + (size_t)b * 2048 * 2048 + h * 64;
  bf16x8 qfh[2][2], qfl[2][2];
#pragma unroll
  for (int m = 0; m < 2; ++m)
#pragma unroll
    for (int kk = 0; kk < 2; ++kk) {
      qfh[m][kk] = *(const bf16x8*)(Qb + (size_t)(wrow_hi + m * 16 + r16) * 2048 + kk * 32 + g * 8);
      qfl[m][kk] = *(const bf16x8*)(Qb + (size_t)(wrow_lo + m * 16 + r16) * 2048 + kk * 32 + g * 8);
    }

  const u16* Kh = Kp + (size_t)(b * 8 + hkv) * 2048 * 64;
  const u16* Vh = Vt + (size_t)(b * 8 + hkv) * 64 * 2048;

  f32x4 accOh[2][4], accOl[2][4];
  float mih[2], lih[2], mil[2], lil[2];
#pragma unroll
  for (int m = 0; m < 2; ++m) {
    mih[m] = -1e30f; lih[m] = 0.f;
    mil[m] = -1e30f; lil[m] = 0.f;
#pragma unroll
    for (int n = 0; n < 4; ++n) { accOh[m][n] = f32x4{0,0,0,0}; accOl[m][n] = f32x4{0,0,0,0}; }
  }

  u16* sPw = sP[w];
  int offp[2][2], offkv[4][2];
#pragma unroll
  for (int m = 0; m < 2; ++m)
#pragma unroll
    for (int kk = 0; kk < 2; ++kk) {
      int row = m * 16 + r16;
      offp[m][kk] = row * 64 + (((kk * 4 + g) ^ (row & 7)) << 3);
    }
#pragma unroll
  for (int n = 0; n < 4; ++n)
#pragma unroll
    for (int kk = 0; kk < 2; ++kk) {
      int row = n * 16 + r16;
      offkv[n][kk] = row * 64 + (((kk * 4 + g) ^ (row & 7)) << 3);
    }

  const int nt_hi = 2 * qhi + 2, nt_lo = 2 * qlo + 2;
  int cur = 0;
  stage64x64(Kh, 64, sK[0]);
  stage64x64(Vh, 2048, sV[0]);
  for (int it = 0; it < nt_hi; ++it) {
    asm volatile("s_waitcnt vmcnt(0)" ::: "memory");
    __syncthreads();
    if (it + 1 < nt_hi) {
      stage64x64(Kh + (size_t)(it + 1) * 64 * 64, 64, sK[cur ^ 1]);
      stage64x64(Vh + (it + 1) * 64, 2048, sV[cur ^ 1]);
    }
    const int kv0 = it * 64;
    attn_tile(sK[cur], sV[cur], sPw, qfh, accOh, mih, lih, wrow_hi, kv0, lane, g, r16, offp, offkv);
    if (it < nt_lo)
      attn_tile(sK[cur], sV[cur], sPw, qfl, accOl, mil, lil, wrow_lo, kv0, lane, g, r16, offp, offkv);
    cur ^= 1;
  }
  // epilogue: accO rows are q = m*16+g*4+j; li lives at lane r16 = g*4+j
#pragma unroll
  for (int m = 0; m < 2; ++m)
#pragma unroll
    for (int j = 0; j < 4; ++j) {
      int src = (lane & 48) | (((lane >> 4) & 3) * 4 + j);
      float lh = bperm_f(src, lih[m]);
      float ll = bperm_f(src, lil[m]);
      int rh = wrow_hi + m * 16 + g * 4 + j;
      int rl = wrow_lo + m * 16 + g * 4 + j;
#pragma unroll
      for (int n = 0; n < 4; ++n) {
        int col = h * 64 + n * 16 + r16;
        Oh[((size_t)b * 2048 + rh) * 2048 + col] = f2bf(accOh[m][n][j] / lh);
        Oh[((size_t)b * 2048 + rl) * 2048 + col] = f2bf(accOl[m][n][j] / ll);
      }
    }
}

__global__ __launch_bounds__(256) void outproj_kernel(const u16* __restrict__ A,
                                                      const u16* __restrict__ WoT,
                                                      float* __restrict__ out) {
  __shared__ __align__(16) u16 sA[2 * 4096];
  __shared__ __align__(16) u16 sB[2 * 4096];
  const int bm = blockIdx.x >> 4, bn = blockIdx.x & 15;
  f32x4 acc[4][4];
  gemm_tile(A, 2048, WoT, 2048, 2048, bm * 128, bn * 128, sA, sB, acc);
  const int t = threadIdx.x, w = t >> 6, lane = t & 63;
  const int wr = w >> 1, wc = w & 1, g = lane >> 4, r16 = lane & 15;
#pragma unroll
  for (int m = 0; m < 4; ++m)
#pragma unroll
    for (int n = 0; n < 4; ++n)
#pragma unroll
      for (int j = 0; j < 4; ++j) {
        int row = bm * 128 + wr * 64 + m * 16 + g * 4 + j;
        int col = bn * 128 + wc * 64 + n * 16 + r16;
        out[(size_t)row * 2048 + col] = acc[m][n][j];
      }
}

extern "C" void kernel_launch(void* const* d_in, const int* in_sizes, int n_in,
                              void* d_out, int out_size, void* d_ws, size_t ws_size,
                              hipStream_t stream) {
  const float* x  = (const float*)d_in[0];
  const float* wq = (const float*)d_in[1];
  const float* wk = (const float*)d_in[2];
  const float* wv = (const float*)d_in[3];
  const float* wo = (const float*)d_in[4];

  const size_t NEED_BYTES = 2ull * (8388608 + 4194304 + 1048576 + 1048576 + 4194304);
  if (ws_size < NEED_BYTES) return;

  float* outf  = (float*)d_out;
  float* koutf = outf + (size_t)8388608;
  float* voutf = koutf + (size_t)2097152;

  u16* Qs  = (u16*)d_out;                 // parked in out region
  u16* Vt  = Qs + (size_t)8388608;        // (B,HKV,HD,S)
  u16* Kbf = Vt + (size_t)2097152;        // (B,HKV,S,HD)

  u16* ws   = (u16*)d_ws;
  u16* xbf  = ws;                         // dead after proj -> reused as Oh
  u16* Oh   = ws;
  u16* wqT  = ws  + (size_t)8388608;
  u16* wkT  = wqT + (size_t)4194304;
  u16* wvT  = wkT + (size_t)1048576;
  u16* woT  = wvT + (size_t)1048576;

  cvt_kernel<<<4096, 256, 0, stream>>>(x, xbf);
  transpose_all<<<dim3(160, 64), dim3(32, 8), 0, stream>>>(wq, wk, wv, wo, wqT, wkT, wvT, woT);

  proj_kernel<<<768, 256, 0, stream>>>(xbf, wqT, wkT, wvT, Qs, koutf, Kbf, voutf, Vt);
  attn_kernel<<<dim3(8, 64), 256, 0, stream>>>(Qs, Kbf, Vt, Oh);
  outproj_kernel<<<512, 256, 0, stream>>>(Oh, woT, outf);
}

// Round 7
// 301.268 us; speedup vs baseline: 1.3479x; 1.0483x over previous
//
#include <hip/hip_runtime.h>

typedef unsigned short u16;
typedef unsigned int u32;
typedef __attribute__((ext_vector_type(8))) __bf16 bf16x8;
typedef __attribute__((ext_vector_type(8))) u16 u16x8;
typedef __attribute__((ext_vector_type(2))) u32 u32x2;
typedef __attribute__((ext_vector_type(4))) float f32x4;

#define DEVI static __device__ __forceinline__

// B=2, S=2048, D=2048, HQ=32, HKV=8, HD=64, G=4, KV_DIM=512, M=B*S=4096
// Inputs f32 (+int32 mask unused). Outputs f32 (out,K,V concat). bf16 internals.

DEVI u16 f2bf(float f) {
  unsigned u = __float_as_uint(f);
  u += 0x7fff + ((u >> 16) & 1);   // RNE
  return (u16)(u >> 16);
}

DEVI u32 cvt_pk_bf16(float lo, float hi) {
  u32 r;
  asm("v_cvt_pk_bf16_f32 %0, %1, %2" : "=v"(r) : "v"(lo), "v"(hi));
  return r;
}

DEVI float bperm_f(int srclane, float v) {
  return __int_as_float(__builtin_amdgcn_ds_bpermute(srclane << 2, __float_as_int(v)));
}

DEVI void gll16(const void* g, void* l) {
  __builtin_amdgcn_global_load_lds((const __attribute__((address_space(1))) void*)g,
                                   (__attribute__((address_space(3))) void*)l, 16, 0, 0);
}

// Stage 128x32 bf16 tile, XOR-swizzled via source (256-thread GEMM blocks).
DEVI void stage128x32(const u16* g, int ld, u16* lds) {
  int t = threadIdx.x, w = t >> 6, l = t & 63;
#pragma unroll
  for (int r = 0; r < 2; ++r) {
    int c = (w * 2 + r) * 64 + l;
    int row = c >> 2;
    int p = (c & 3) ^ (row & 3);
    gll16(g + (size_t)row * ld + p * 8, (char*)lds + (w * 2 + r) * 1024);
  }
}

// Stage 64x64 bf16 tile, XOR-swizzled, for 128-thread (2-wave) attention blocks.
DEVI void stage64x64_2w(const u16* g, int ld, u16* lds) {
  int t = threadIdx.x, w = t >> 6, l = t & 63;
#pragma unroll
  for (int r = 0; r < 4; ++r) {
    int c = (w * 4 + r) * 64 + l;
    int row = c >> 3;
    int p = (c & 7) ^ (row & 7);
    gll16(g + (size_t)row * ld + p * 8, (char*)lds + (w * 4 + r) * 1024);
  }
}

// 128x128 tile GEMM (unchanged, passing).
DEVI void gemm_tile(const u16* A, int lda, const u16* Bt, int ldb, int K,
                    int m0, int n0, u16* sA, u16* sB, f32x4 acc[4][4]) {
  const int t = threadIdx.x, w = t >> 6, lane = t & 63;
  const int wr = w >> 1, wc = w & 1, g = lane >> 4, r16 = lane & 15;
  int offa[4], offb[4];
#pragma unroll
  for (int m = 0; m < 4; ++m) {
    int row = wr * 64 + m * 16 + r16;
    offa[m] = row * 32 + ((g ^ (row & 3)) << 3);
  }
#pragma unroll
  for (int n = 0; n < 4; ++n) {
    int row = wc * 64 + n * 16 + r16;
    offb[n] = row * 32 + ((g ^ (row & 3)) << 3);
  }
#pragma unroll
  for (int m = 0; m < 4; ++m)
#pragma unroll
    for (int n = 0; n < 4; ++n) acc[m][n] = f32x4{0.f, 0.f, 0.f, 0.f};

  const u16* At = A + (size_t)m0 * lda;
  const u16* Bb = Bt + (size_t)n0 * ldb;
  stage128x32(At, lda, sA);
  stage128x32(Bb, ldb, sB);
  asm volatile("s_waitcnt vmcnt(0)" ::: "memory");
  __syncthreads();
  const int nk = K >> 5;
  int cur = 0;
  for (int kt = 0; kt < nk; ++kt) {
    if (kt + 1 < nk) {
      stage128x32(At + (kt + 1) * 32, lda, sA + (cur ^ 1) * 4096);
      stage128x32(Bb + (kt + 1) * 32, ldb, sB + (cur ^ 1) * 4096);
    }
    bf16x8 av[4], bv[4];
#pragma unroll
    for (int m = 0; m < 4; ++m) av[m] = *(const bf16x8*)(sA + cur * 4096 + offa[m]);
#pragma unroll
    for (int n = 0; n < 4; ++n) bv[n] = *(const bf16x8*)(sB + cur * 4096 + offb[n]);
#pragma unroll
    for (int m = 0; m < 4; ++m)
#pragma unroll
      for (int n = 0; n < 4; ++n)
        acc[m][n] = __builtin_amdgcn_mfma_f32_16x16x32_bf16(av[m], bv[n], acc[m][n], 0, 0, 0);
    asm volatile("s_waitcnt vmcnt(0)" ::: "memory");
    __syncthreads();
    cur ^= 1;
  }
}

__global__ __launch_bounds__(256) void cvt_kernel(const float* __restrict__ src,
                                                  u16* __restrict__ dst) {
  int i = blockIdx.x * 256 + threadIdx.x;
  float4 a = ((const float4*)src)[2 * i];
  float4 b = ((const float4*)src)[2 * i + 1];
  u16x8 o;
  o[0] = f2bf(a.x); o[1] = f2bf(a.y); o[2] = f2bf(a.z); o[3] = f2bf(a.w);
  o[4] = f2bf(b.x); o[5] = f2bf(b.y); o[6] = f2bf(b.z); o[7] = f2bf(b.w);
  ((u16x8*)dst)[i] = o;
}

__global__ __launch_bounds__(256) void transpose_all(
    const float* __restrict__ wq, const float* __restrict__ wk,
    const float* __restrict__ wv, const float* __restrict__ wo,
    u16* __restrict__ wqT, u16* __restrict__ wkT,
    u16* __restrict__ wvT, u16* __restrict__ woT) {
  __shared__ float tle[32][33];
  int bxr = blockIdx.x;
  const float* src; u16* dst; int C, bxl;
  if (bxr < 64)       { src = wq; dst = wqT; C = 2048; bxl = bxr; }
  else if (bxr < 80)  { src = wk; dst = wkT; C = 512;  bxl = bxr - 64; }
  else if (bxr < 96)  { src = wv; dst = wvT; C = 512;  bxl = bxr - 80; }
  else                { src = wo; dst = woT; C = 2048; bxl = bxr - 96; }
  int bx = bxl * 32, by = blockIdx.y * 32;
  int tx = threadIdx.x, ty = threadIdx.y;  // 32 x 8
#pragma unroll
  for (int i = 0; i < 32; i += 8) tle[ty + i][tx] = src[(size_t)(by + ty + i) * C + bx + tx];
  __syncthreads();
#pragma unroll
  for (int i = 0; i < 32; i += 8)
    dst[(size_t)(bx + ty + i) * 2048 + by + tx] = f2bf(tle[tx][ty + i]);
}

__global__ __launch_bounds__(256) void proj_kernel(
    const u16* __restrict__ x, const u16* __restrict__ wqT, const u16* __restrict__ wkT,
    const u16* __restrict__ wvT, u16* __restrict__ qout, float* __restrict__ koutf,
    u16* __restrict__ kbf, float* __restrict__ voutf, u16* __restrict__ vtout) {
  __shared__ __align__(16) u16 sA[2 * 4096];
  __shared__ __align__(16) u16 sB[2 * 4096];
  const int bid = blockIdx.x;
  int mode, bm, bn;
  const u16* Bt;
  if (bid < 512) { mode = 0; bm = bid >> 4; bn = bid & 15; Bt = wqT; }
  else if (bid < 640) { mode = 1; int i = bid - 512; bm = i >> 2; bn = i & 3; Bt = wkT; }
  else { mode = 2; int i = bid - 640; bm = i >> 2; bn = i & 3; Bt = wvT; }

  f32x4 acc[4][4];
  gemm_tile(x, 2048, Bt, 2048, 2048, bm * 128, bn * 128, sA, sB, acc);

  const int t = threadIdx.x, w = t >> 6, lane = t & 63;
  const int wr = w >> 1, wc = w & 1, g = lane >> 4, r16 = lane & 15;
  const float QSCALE = 0.125f * 1.44269504088896340736f;  // 1/sqrt(64) * log2(e)
#pragma unroll
  for (int m = 0; m < 4; ++m)
#pragma unroll
    for (int n = 0; n < 4; ++n)
#pragma unroll
      for (int j = 0; j < 4; ++j) {
        int row = bm * 128 + wr * 64 + m * 16 + g * 4 + j;
        int col = bn * 128 + wc * 64 + n * 16 + r16;
        float v = acc[m][n][j];
        if (mode == 0) {
          qout[(size_t)row * 2048 + col] = f2bf(v * QSCALE);
        } else {
          int b = row >> 11, s = row & 2047;
          int h = col >> 6, d = col & 63;
          size_t idx = ((size_t)(b * 8 + h) * 2048 + s) * 64 + d;
          if (mode == 1) {
            koutf[idx] = v;
            kbf[idx] = f2bf(v);
          } else {
            voutf[idx] = v;
            vtout[((size_t)(b * 8 + h) * 64 + d) * 2048 + s] = f2bf(v);
          }
        }
      }
}

// One 32-q-row x 64-kv tile step, swapped QK^T + defer-max + setprio.
DEVI void attn_tile(const u16* sKc, const u16* sVc, u16* sPw,
                    const bf16x8 (&qf)[2][2], f32x4 (&accO)[2][4],
                    float (&mi)[2], float (&li)[2],
                    int wrow0, int kv0, int lane, int g, int r16,
                    const int (&offp)[2][2], const int (&offkv)[4][2]) {
  if (kv0 > wrow0 + 31) return;
  f32x4 st[2][4];
#pragma unroll
  for (int m = 0; m < 2; ++m)
#pragma unroll
    for (int n = 0; n < 4; ++n) st[m][n] = f32x4{0.f, 0.f, 0.f, 0.f};
  __builtin_amdgcn_s_setprio(1);
#pragma unroll
  for (int kk = 0; kk < 2; ++kk)
#pragma unroll
    for (int n = 0; n < 4; ++n) {
      bf16x8 kf = *(const bf16x8*)(sKc + offkv[n][kk]);
#pragma unroll
      for (int m = 0; m < 2; ++m)
        st[m][n] = __builtin_amdgcn_mfma_f32_16x16x32_bf16(kf, qf[m][kk], st[m][n], 0, 0, 0);
    }
  __builtin_amdgcn_s_setprio(0);
  if (kv0 + 63 > wrow0) {  // diagonal: causal mask. kv = kv0+n*16+g*4+j, q = wrow0+m*16+r16
#pragma unroll
    for (int m = 0; m < 2; ++m) {
      int qg = wrow0 + m * 16 + r16;
#pragma unroll
      for (int n = 0; n < 4; ++n)
#pragma unroll
        for (int j = 0; j < 4; ++j) {
          int kvg = kv0 + n * 16 + g * 4 + j;
          if (kvg > qg) st[m][n][j] = -1e30f;
        }
    }
  }
#pragma unroll
  for (int m = 0; m < 2; ++m) {
    float a0 = fmaxf(fmaxf(st[m][0][0], st[m][0][1]), fmaxf(st[m][0][2], st[m][0][3]));
    float a1 = fmaxf(fmaxf(st[m][1][0], st[m][1][1]), fmaxf(st[m][1][2], st[m][1][3]));
    float a2 = fmaxf(fmaxf(st[m][2][0], st[m][2][1]), fmaxf(st[m][2][2], st[m][2][3]));
    float a3 = fmaxf(fmaxf(st[m][3][0], st[m][3][1]), fmaxf(st[m][3][2], st[m][3][3]));
    float pmax = fmaxf(fmaxf(a0, a1), fmaxf(a2, a3));
    pmax = fmaxf(pmax, __shfl_xor(pmax, 16));
    pmax = fmaxf(pmax, __shfl_xor(pmax, 32));
    // defer-max: only rescale when the running max grows by > 8 (exp2 domain)
    if (!__all(pmax - mi[m] <= 8.0f)) {
      float mn = fmaxf(mi[m], pmax);
      float scl = exp2f(mi[m] - mn);
      mi[m] = mn;
      li[m] *= scl;
#pragma unroll
      for (int j = 0; j < 4; ++j) {
        float sj = bperm_f((lane & 48) | (((lane >> 4) & 3) * 4 + j), scl);
#pragma unroll
        for (int n = 0; n < 4; ++n) accO[m][n][j] *= sj;
      }
    }
    float mn = mi[m];
    float rs = 0.f;
    u32 pk[4][2];
#pragma unroll
    for (int n = 0; n < 4; ++n) {
      float p0 = exp2f(st[m][n][0] - mn);
      float p1 = exp2f(st[m][n][1] - mn);
      float p2 = exp2f(st[m][n][2] - mn);
      float p3 = exp2f(st[m][n][3] - mn);
      rs += (p0 + p1) + (p2 + p3);
      pk[n][0] = cvt_pk_bf16(p0, p1);
      pk[n][1] = cvt_pk_bf16(p2, p3);
    }
    rs += __shfl_xor(rs, 16);
    rs += __shfl_xor(rs, 32);
    li[m] += rs;
    int row = m * 16 + r16;
    u16* pbase = sPw + row * 64 + (g & 1) * 4;
#pragma unroll
    for (int n = 0; n < 4; ++n) {
      u32x2 wv2 = {pk[n][0], pk[n][1]};
      *(u32x2*)(pbase + (((n * 2 + (g >> 1)) ^ (row & 7)) << 3)) = wv2;
    }
  }
  asm volatile("s_waitcnt lgkmcnt(0)" ::: "memory");
  __builtin_amdgcn_s_setprio(1);
#pragma unroll
  for (int kk = 0; kk < 2; ++kk) {
    bf16x8 pa[2];
#pragma unroll
    for (int m = 0; m < 2; ++m) pa[m] = *(const bf16x8*)(sPw + offp[m][kk]);
#pragma unroll
    for (int n = 0; n < 4; ++n) {
      bf16x8 vf = *(const bf16x8*)(sVc + offkv[n][kk]);
#pragma unroll
      for (int m = 0; m < 2; ++m)
        accO[m][n] = __builtin_amdgcn_mfma_f32_16x16x32_bf16(pa[m], vf, accO[m][n], 0, 0, 0);
    }
  }
  __builtin_amdgcn_s_setprio(0);
}

// 2-wave blocks over 64-row q-subtiles; balanced pairing (qhi=31-bx, qlo=bx).
// Grid 16x64 = 1024 blocks -> 4 blocks/CU, 2 waves/SIMD.
__global__ __launch_bounds__(128) void attn_kernel(
    const u16* __restrict__ Q, const u16* __restrict__ Kp,
    const u16* __restrict__ Vt, u16* __restrict__ Oh) {
  __shared__ __align__(16) u16 sK[2][4096];
  __shared__ __align__(16) u16 sV[2][4096];
  __shared__ __align__(16) u16 sP[2][2048];
  const int bx = blockIdx.x, bh = blockIdx.y;
  const int qhi = 31 - bx, qlo = bx;
  const int b = bh >> 5, h = bh & 31, hkv = h >> 2;
  const int t = threadIdx.x, w = t >> 6, lane = t & 63;
  const int g = lane >> 4, r16 = lane & 15;
  const int wrow_hi = qhi * 64 + w * 32;
  const int wrow_lo = qlo * 64 + w * 32;

  const u16* Qb = Q + (size_t)b * 2048 * 2048 + h * 64;
  bf16x8 qfh[2][2], qfl[2][2];
#pragma unroll
  for (int m = 0; m < 2; ++m)
#pragma unroll
    for (int kk = 0; kk < 2; ++kk) {
      qfh[m][kk] = *(const bf16x8*)(Qb + (size_t)(wrow_hi + m * 16 + r16) * 2048 + kk * 32 + g * 8);
      qfl[m][kk] = *(const bf16x8*)(Qb + (size_t)(wrow_lo + m * 16 + r16) * 2048 + kk * 32 + g * 8);
    }

  const u16* Kh = Kp + (size_t)(b * 8 + hkv) * 2048 * 64;
  const u16* Vh = Vt + (size_t)(b * 8 + hkv) * 64 * 2048;

  f32x4 accOh[2][4], accOl[2][4];
  float mih[2], lih[2], mil[2], lil[2];
#pragma unroll
  for (int m = 0; m < 2; ++m) {
    mih[m] = -1e30f; lih[m] = 0.f;
    mil[m] = -1e30f; lil[m] = 0.f;
#pragma unroll
    for (int n = 0; n < 4; ++n) { accOh[m][n] = f32x4{0,0,0,0}; accOl[m][n] = f32x4{0,0,0,0}; }
  }

  u16* sPw = sP[w];
  int offp[2][2], offkv[4][2];
#pragma unroll
  for (int m = 0; m < 2; ++m)
#pragma unroll
    for (int kk = 0; kk < 2; ++kk) {
      int row = m * 16 + r16;
      offp[m][kk] = row * 64 + (((kk * 4 + g) ^ (row & 7)) << 3);
    }
#pragma unroll
  for (int n = 0; n < 4; ++n)
#pragma unroll
    for (int kk = 0; kk < 2; ++kk) {
      int row = n * 16 + r16;
      offkv[n][kk] = row * 64 + (((kk * 4 + g) ^ (row & 7)) << 3);
    }

  const int nt_hi = qhi + 1, nt_lo = qlo + 1;
  int cur = 0;
  stage64x64_2w(Kh, 64, sK[0]);
  stage64x64_2w(Vh, 2048, sV[0]);
  for (int it = 0; it < nt_hi; ++it) {
    asm volatile("s_waitcnt vmcnt(0)" ::: "memory");
    __syncthreads();
    if (it + 1 < nt_hi) {
      stage64x64_2w(Kh + (size_t)(it + 1) * 64 * 64, 64, sK[cur ^ 1]);
      stage64x64_2w(Vh + (it + 1) * 64, 2048, sV[cur ^ 1]);
    }
    const int kv0 = it * 64;
    attn_tile(sK[cur], sV[cur], sPw, qfh, accOh, mih, lih, wrow_hi, kv0, lane, g, r16, offp, offkv);
    if (it < nt_lo)
      attn_tile(sK[cur], sV[cur], sPw, qfl, accOl, mil, lil, wrow_lo, kv0, lane, g, r16, offp, offkv);
    cur ^= 1;
  }
  // epilogue: accO rows are q = m*16+g*4+j; li lives at lane r16 = g*4+j
#pragma unroll
  for (int m = 0; m < 2; ++m)
#pragma unroll
    for (int j = 0; j < 4; ++j) {
      int src = (lane & 48) | (((lane >> 4) & 3) * 4 + j);
      float lh = bperm_f(src, lih[m]);
      float ll = bperm_f(src, lil[m]);
      int rh = wrow_hi + m * 16 + g * 4 + j;
      int rl = wrow_lo + m * 16 + g * 4 + j;
#pragma unroll
      for (int n = 0; n < 4; ++n) {
        int col = h * 64 + n * 16 + r16;
        Oh[((size_t)b * 2048 + rh) * 2048 + col] = f2bf(accOh[m][n][j] / lh);
        Oh[((size_t)b * 2048 + rl) * 2048 + col] = f2bf(accOl[m][n][j] / ll);
      }
    }
}

__global__ __launch_bounds__(256) void outproj_kernel(const u16* __restrict__ A,
                                                      const u16* __restrict__ WoT,
                                                      float* __restrict__ out) {
  __shared__ __align__(16) u16 sA[2 * 4096];
  __shared__ __align__(16) u16 sB[2 * 4096];
  const int bm = blockIdx.x >> 4, bn = blockIdx.x & 15;
  f32x4 acc[4][4];
  gemm_tile(A, 2048, WoT, 2048, 2048, bm * 128, bn * 128, sA, sB, acc);
  const int t = threadIdx.x, w = t >> 6, lane = t & 63;
  const int wr = w >> 1, wc = w & 1, g = lane >> 4, r16 = lane & 15;
#pragma unroll
  for (int m = 0; m < 4; ++m)
#pragma unroll
    for (int n = 0; n < 4; ++n)
#pragma unroll
      for (int j = 0; j < 4; ++j) {
        int row = bm * 128 + wr * 64 + m * 16 + g * 4 + j;
        int col = bn * 128 + wc * 64 + n * 16 + r16;
        out[(size_t)row * 2048 + col] = acc[m][n][j];
      }
}

extern "C" void kernel_launch(void* const* d_in, const int* in_sizes, int n_in,
                              void* d_out, int out_size, void* d_ws, size_t ws_size,
                              hipStream_t stream) {
  const float* x  = (const float*)d_in[0];
  const float* wq = (const float*)d_in[1];
  const float* wk = (const float*)d_in[2];
  const float* wv = (const float*)d_in[3];
  const float* wo = (const float*)d_in[4];

  const size_t NEED_BYTES = 2ull * (8388608 + 4194304 + 1048576 + 1048576 + 4194304);
  if (ws_size < NEED_BYTES) return;

  float* outf  = (float*)d_out;
  float* koutf = outf + (size_t)8388608;
  float* voutf = koutf + (size_t)2097152;

  u16* Qs  = (u16*)d_out;                 // parked in out region
  u16* Vt  = Qs + (size_t)8388608;        // (B,HKV,HD,S)
  u16* Kbf = Vt + (size_t)2097152;        // (B,HKV,S,HD)

  u16* ws   = (u16*)d_ws;
  u16* xbf  = ws;                         // dead after proj -> reused as Oh
  u16* Oh   = ws;
  u16* wqT  = ws  + (size_t)8388608;
  u16* wkT  = wqT + (size_t)4194304;
  u16* wvT  = wkT + (size_t)1048576;
  u16* woT  = wvT + (size_t)1048576;

  cvt_kernel<<<4096, 256, 0, stream>>>(x, xbf);
  transpose_all<<<dim3(160, 64), dim3(32, 8), 0, stream>>>(wq, wk, wv, wo, wqT, wkT, wvT, woT);

  proj_kernel<<<768, 256, 0, stream>>>(xbf, wqT, wkT, wvT, Qs, koutf, Kbf, voutf, Vt);
  attn_kernel<<<dim3(16, 64), 128, 0, stream>>>(Qs, Kbf, Vt, Oh);
  outproj_kernel<<<512, 256, 0, stream>>>(Oh, woT, outf);
}

// Round 13
// 282.363 us; speedup vs baseline: 1.4381x; 1.0670x over previous
//
#include <hip/hip_runtime.h>

typedef unsigned short u16;
typedef unsigned int u32;
typedef __attribute__((ext_vector_type(8))) __bf16 bf16x8;
typedef __attribute__((ext_vector_type(8))) u16 u16x8;
typedef __attribute__((ext_vector_type(2))) u32 u32x2;
typedef __attribute__((ext_vector_type(4))) float f32x4;
typedef __attribute__((ext_vector_type(16))) float f32x16;

#define DEVI static __device__ __forceinline__

// B=2, S=2048, D=2048, HQ=32, HKV=8, HD=64, G=4, KV_DIM=512, M=B*S=4096
// Inputs f32 (+int32 mask unused). Outputs f32 (out,K,V concat). bf16 internals.

DEVI u16 f2bf(float f) {
  unsigned u = __float_as_uint(f);
  u += 0x7fff + ((u >> 16) & 1);   // RNE
  return (u16)(u >> 16);
}

DEVI u32 cvt_pk_bf16(float lo, float hi) {
  u32 r;
  asm("v_cvt_pk_bf16_f32 %0, %1, %2" : "=v"(r) : "v"(lo), "v"(hi));
  return r;
}

DEVI float bperm_f(int srclane, float v) {
  return __int_as_float(__builtin_amdgcn_ds_bpermute(srclane << 2, __float_as_int(v)));
}

DEVI void gll16(const void* g, void* l) {
  __builtin_amdgcn_global_load_lds((const __attribute__((address_space(1))) void*)g,
                                   (__attribute__((address_space(3))) void*)l, 16, 0, 0);
}

// Stage 128x32 bf16 tile, XOR-swizzled via source (256-thread GEMM blocks).
DEVI void stage128x32(const u16* g, int ld, u16* lds) {
  int t = threadIdx.x, w = t >> 6, l = t & 63;
#pragma unroll
  for (int r = 0; r < 2; ++r) {
    int c = (w * 2 + r) * 64 + l;
    int row = c >> 2;
    int p = (c & 3) ^ (row & 3);
    gll16(g + (size_t)row * ld + p * 8, (char*)lds + (w * 2 + r) * 1024);
  }
}

// Stage 64x64 bf16 tile, XOR-swizzled (256 threads = 4 waves, 2 chunks/thread).
DEVI void stage64x64(const u16* g, int ld, u16* lds) {
  int t = threadIdx.x, w = t >> 6, l = t & 63;
#pragma unroll
  for (int r = 0; r < 2; ++r) {
    int c = (w * 2 + r) * 64 + l;
    int row = c >> 3;
    int p = (c & 7) ^ (row & 7);
    gll16(g + (size_t)row * ld + p * 8, (char*)lds + (w * 2 + r) * 1024);
  }
}

// 128x128 tile GEMM (unchanged, passing).
DEVI void gemm_tile(const u16* A, int lda, const u16* Bt, int ldb, int K,
                    int m0, int n0, u16* sA, u16* sB, f32x4 acc[4][4]) {
  const int t = threadIdx.x, w = t >> 6, lane = t & 63;
  const int wr = w >> 1, wc = w & 1, g = lane >> 4, r16 = lane & 15;
  int offa[4], offb[4];
#pragma unroll
  for (int m = 0; m < 4; ++m) {
    int row = wr * 64 + m * 16 + r16;
    offa[m] = row * 32 + ((g ^ (row & 3)) << 3);
  }
#pragma unroll
  for (int n = 0; n < 4; ++n) {
    int row = wc * 64 + n * 16 + r16;
    offb[n] = row * 32 + ((g ^ (row & 3)) << 3);
  }
#pragma unroll
  for (int m = 0; m < 4; ++m)
#pragma unroll
    for (int n = 0; n < 4; ++n) acc[m][n] = f32x4{0.f, 0.f, 0.f, 0.f};

  const u16* At = A + (size_t)m0 * lda;
  const u16* Bb = Bt + (size_t)n0 * ldb;
  stage128x32(At, lda, sA);
  stage128x32(Bb, ldb, sB);
  asm volatile("s_waitcnt vmcnt(0)" ::: "memory");
  __syncthreads();
  const int nk = K >> 5;
  int cur = 0;
  for (int kt = 0; kt < nk; ++kt) {
    if (kt + 1 < nk) {
      stage128x32(At + (kt + 1) * 32, lda, sA + (cur ^ 1) * 4096);
      stage128x32(Bb + (kt + 1) * 32, ldb, sB + (cur ^ 1) * 4096);
    }
    bf16x8 av[4], bv[4];
#pragma unroll
    for (int m = 0; m < 4; ++m) av[m] = *(const bf16x8*)(sA + cur * 4096 + offa[m]);
#pragma unroll
    for (int n = 0; n < 4; ++n) bv[n] = *(const bf16x8*)(sB + cur * 4096 + offb[n]);
#pragma unroll
    for (int m = 0; m < 4; ++m)
#pragma unroll
      for (int n = 0; n < 4; ++n)
        acc[m][n] = __builtin_amdgcn_mfma_f32_16x16x32_bf16(av[m], bv[n], acc[m][n], 0, 0, 0);
    asm volatile("s_waitcnt vmcnt(0)" ::: "memory");
    __syncthreads();
    cur ^= 1;
  }
}

__global__ __launch_bounds__(256) void cvt_kernel(const float* __restrict__ src,
                                                  u16* __restrict__ dst) {
  int i = blockIdx.x * 256 + threadIdx.x;
  float4 a = ((const float4*)src)[2 * i];
  float4 b = ((const float4*)src)[2 * i + 1];
  u16x8 o;
  o[0] = f2bf(a.x); o[1] = f2bf(a.y); o[2] = f2bf(a.z); o[3] = f2bf(a.w);
  o[4] = f2bf(b.x); o[5] = f2bf(b.y); o[6] = f2bf(b.z); o[7] = f2bf(b.w);
  ((u16x8*)dst)[i] = o;
}

__global__ __launch_bounds__(256) void transpose_all(
    const float* __restrict__ wq, const float* __restrict__ wk,
    const float* __restrict__ wv, const float* __restrict__ wo,
    u16* __restrict__ wqT, u16* __restrict__ wkT,
    u16* __restrict__ wvT, u16* __restrict__ woT) {
  __shared__ float tle[32][33];
  int bxr = blockIdx.x;
  const float* src; u16* dst; int C, bxl;
  if (bxr < 64)       { src = wq; dst = wqT; C = 2048; bxl = bxr; }
  else if (bxr < 80)  { src = wk; dst = wkT; C = 512;  bxl = bxr - 64; }
  else if (bxr < 96)  { src = wv; dst = wvT; C = 512;  bxl = bxr - 80; }
  else                { src = wo; dst = woT; C = 2048; bxl = bxr - 96; }
  int bx = bxl * 32, by = blockIdx.y * 32;
  int tx = threadIdx.x, ty = threadIdx.y;  // 32 x 8
#pragma unroll
  for (int i = 0; i < 32; i += 8) tle[ty + i][tx] = src[(size_t)(by + ty + i) * C + bx + tx];
  __syncthreads();
#pragma unroll
  for (int i = 0; i < 32; i += 8)
    dst[(size_t)(bx + ty + i) * 2048 + by + tx] = f2bf(tle[tx][ty + i]);
}

__global__ __launch_bounds__(256) void proj_kernel(
    const u16* __restrict__ x, const u16* __restrict__ wqT, const u16* __restrict__ wkT,
    const u16* __restrict__ wvT, u16* __restrict__ qout, float* __restrict__ koutf,
    u16* __restrict__ kbf, float* __restrict__ voutf, u16* __restrict__ vtout) {
  __shared__ __align__(16) u16 sA[2 * 4096];
  __shared__ __align__(16) u16 sB[2 * 4096];
  const int bid = blockIdx.x;
  int mode, bm, bn;
  const u16* Bt;
  if (bid < 512) { mode = 0; bm = bid >> 4; bn = bid & 15; Bt = wqT; }
  else if (bid < 640) { mode = 1; int i = bid - 512; bm = i >> 2; bn = i & 3; Bt = wkT; }
  else { mode = 2; int i = bid - 640; bm = i >> 2; bn = i & 3; Bt = wvT; }

  f32x4 acc[4][4];
  gemm_tile(x, 2048, Bt, 2048, 2048, bm * 128, bn * 128, sA, sB, acc);

  const int t = threadIdx.x, w = t >> 6, lane = t & 63;
  const int wr = w >> 1, wc = w & 1, g = lane >> 4, r16 = lane & 15;
  const float QSCALE = 0.125f * 1.44269504088896340736f;  // 1/sqrt(64) * log2(e)
#pragma unroll
  for (int m = 0; m < 4; ++m)
#pragma unroll
    for (int n = 0; n < 4; ++n)
#pragma unroll
      for (int j = 0; j < 4; ++j) {
        int row = bm * 128 + wr * 64 + m * 16 + g * 4 + j;
        int col = bn * 128 + wc * 64 + n * 16 + r16;
        float v = acc[m][n][j];
        if (mode == 0) {
          qout[(size_t)row * 2048 + col] = f2bf(v * QSCALE);
        } else {
          int b = row >> 11, s = row & 2047;
          int h = col >> 6, d = col & 63;
          size_t idx = ((size_t)(b * 8 + h) * 2048 + s) * 64 + d;
          if (mode == 1) {
            koutf[idx] = v;
            kbf[idx] = f2bf(v);
          } else {
            voutf[idx] = v;
            vtout[((size_t)(b * 8 + h) * 64 + d) * 2048 + s] = f2bf(v);
          }
        }
      }
}

// One 32-q-row x 64-kv tile, 32x32 swapped MFMA. P goes through a per-wave
// swizzled LDS buffer (proven r7 pattern); cross-half reduce via __shfl_xor.
DEVI void attn_tile32(const u16* sKc, const u16* sVc, u16* sPw,
                      const bf16x8 (&qf)[4], f32x16 (&accO0)[1], f32x16 (&accO1)[1],
                      float &mi, float &li,
                      int wrow0, int kv0, int lane,
                      const int (&offk)[2][4], const int (&offv)[4][2],
                      const int (&offp)[4]) {
  if (kv0 > wrow0 + 31) return;
  const int l5 = lane >> 5, l31 = lane & 31;
  f32x16 st[2];
#pragma unroll
  for (int i = 0; i < 16; ++i) { st[0][i] = 0.f; st[1][i] = 0.f; }
  __builtin_amdgcn_s_setprio(1);
#pragma unroll
  for (int kd = 0; kd < 4; ++kd)
#pragma unroll
    for (int kb = 0; kb < 2; ++kb) {
      bf16x8 kf = *(const bf16x8*)(sKc + offk[kb][kd]);
      st[kb] = __builtin_amdgcn_mfma_f32_32x32x16_bf16(kf, qf[kd], st[kb], 0, 0, 0);
    }
  __builtin_amdgcn_s_setprio(0);
  if (kv0 + 63 > wrow0) {  // diagonal: causal mask
    int qg = wrow0 + l31;
#pragma unroll
    for (int kb = 0; kb < 2; ++kb)
#pragma unroll
      for (int r = 0; r < 16; ++r) {
        int kvg = kv0 + kb * 32 + (r & 3) + 8 * (r >> 2) + 4 * l5;
        if (kvg > qg) st[kb][r] = -1e30f;
      }
  }
  float pmax = st[0][0];
#pragma unroll
  for (int r = 1; r < 16; ++r) pmax = fmaxf(pmax, st[0][r]);
#pragma unroll
  for (int r = 0; r < 16; ++r) pmax = fmaxf(pmax, st[1][r]);
  pmax = fmaxf(pmax, __shfl_xor(pmax, 32));
  // defer-max: rescale only when running max grows by >8 (exp2 domain)
  if (!__all(pmax - mi <= 8.0f)) {
    float mn = fmaxf(mi, pmax);
    float scl = exp2f(mi - mn);
    mi = mn; li *= scl;
#pragma unroll
    for (int r = 0; r < 16; ++r) {
      int qp = (r & 3) + 8 * (r >> 2) + 4 * l5;
      float sj = bperm_f(qp, scl);
      accO0[0][r] *= sj;
      accO1[0][r] *= sj;
    }
  }
  float rs = 0.f;
#pragma unroll
  for (int kb = 0; kb < 2; ++kb)
#pragma unroll
    for (int r = 0; r < 16; ++r) { st[kb][r] = exp2f(st[kb][r] - mi); rs += st[kb][r]; }
  rs += __shfl_xor(rs, 32);
  li += rs;
  // P -> per-wave LDS, XOR-swizzled. Lane holds P[q=l31][kv = kb*32+8t+4*l5 .. +3]
  // (regmap (r&3)+8*(r>>2)+4*l5 makes st[kb][4t..4t+3] four consecutive kv).
  {
    u16* base = sPw + l31 * 64;
#pragma unroll
    for (int kb = 0; kb < 2; ++kb)
#pragma unroll
      for (int tt = 0; tt < 4; ++tt) {
        u32 lo = cvt_pk_bf16(st[kb][4 * tt + 0], st[kb][4 * tt + 1]);
        u32 hi = cvt_pk_bf16(st[kb][4 * tt + 2], st[kb][4 * tt + 3]);
        int chunk = kb * 4 + tt;                    // kv chunk of 8; half = l5
        u32x2 w2 = {lo, hi};
        *(u32x2*)(base + ((chunk ^ (l31 & 7)) << 3) + l5 * 4) = w2;
      }
  }
  asm volatile("s_waitcnt lgkmcnt(0)" ::: "memory");
  __builtin_amdgcn_s_setprio(1);
#pragma unroll
  for (int ks = 0; ks < 4; ++ks) {
    bf16x8 pa = *(const bf16x8*)(sPw + offp[ks]);
    bf16x8 v0 = *(const bf16x8*)(sVc + offv[ks][0]);
    bf16x8 v1 = *(const bf16x8*)(sVc + offv[ks][1]);
    accO0[0] = __builtin_amdgcn_mfma_f32_32x32x16_bf16(pa, v0, accO0[0], 0, 0, 0);
    accO1[0] = __builtin_amdgcn_mfma_f32_32x32x16_bf16(pa, v1, accO1[0], 0, 0, 0);
  }
  __builtin_amdgcn_s_setprio(0);
}

// 4 waves x 32 q-rows; balanced pairs (qhi=15-bx, qlo=bx); XCD-local (b,h).
__global__ __launch_bounds__(256) void attn_kernel(
    const u16* __restrict__ Q, const u16* __restrict__ Kp,
    const u16* __restrict__ Vt, u16* __restrict__ Oh) {
  __shared__ __align__(16) u16 sK[2][4096];
  __shared__ __align__(16) u16 sV[2][4096];
  __shared__ __align__(16) u16 sP[4][2048];
  const int blk = blockIdx.x;
  const int bh = (blk & 7) * 8 + ((blk >> 3) & 7);  // XCD swizzle
  const int bx = blk >> 6;                          // 0..7
  const int qbhi = 15 - bx, qblo = bx;
  const int b = bh >> 5, h = bh & 31, hkv = h >> 2;
  const int t = threadIdx.x, w = t >> 6, lane = t & 63;
  const int l5 = lane >> 5, l31 = lane & 31;
  const int wrow_hi = qbhi * 128 + w * 32;
  const int wrow_lo = qblo * 128 + w * 32;

  int offk[2][4], offv[4][2], offp[4];
#pragma unroll
  for (int kb = 0; kb < 2; ++kb) {
    int row = kb * 32 + l31;
#pragma unroll
    for (int kd = 0; kd < 4; ++kd)
      offk[kb][kd] = row * 64 + (((kd * 2 + l5) ^ (row & 7)) << 3);
  }
#pragma unroll
  for (int ks = 0; ks < 4; ++ks) {
    offp[ks] = l31 * 64 + (((ks * 2 + l5) ^ (l31 & 7)) << 3);
#pragma unroll
    for (int nd = 0; nd < 2; ++nd) {
      int rd = nd * 32 + l31;
      offv[ks][nd] = rd * 64 + (((ks * 2 + l5) ^ (rd & 7)) << 3);
    }
  }

  const u16* Qb = Q + (size_t)b * 2048 * 2048 + h * 64 + l5 * 8;
  bf16x8 qfh[4], qfl[4];
#pragma unroll
  for (int kd = 0; kd < 4; ++kd) {
    qfh[kd] = *(const bf16x8*)(Qb + (size_t)(wrow_hi + l31) * 2048 + kd * 16);
    qfl[kd] = *(const bf16x8*)(Qb + (size_t)(wrow_lo + l31) * 2048 + kd * 16);
  }

  const u16* Kh = Kp + (size_t)(b * 8 + hkv) * 2048 * 64;
  const u16* Vh = Vt + (size_t)(b * 8 + hkv) * 64 * 2048;

  f32x16 aoh0[1], aoh1[1], aol0[1], aol1[1];
#pragma unroll
  for (int i = 0; i < 16; ++i) { aoh0[0][i] = 0.f; aoh1[0][i] = 0.f; aol0[0][i] = 0.f; aol1[0][i] = 0.f; }
  float mih = -1e30f, lih = 0.f, mil = -1e30f, lil = 0.f;

  const int nt_hi = 2 * (qbhi + 1), nt_lo = 2 * (qblo + 1);
  int cur = 0;
  stage64x64(Kh, 64, sK[0]);
  stage64x64(Vh, 2048, sV[0]);
  for (int it = 0; it < nt_hi; ++it) {
    asm volatile("s_waitcnt vmcnt(0)" ::: "memory");
    __syncthreads();
    if (it + 1 < nt_hi) {
      stage64x64(Kh + (size_t)(it + 1) * 64 * 64, 64, sK[cur ^ 1]);
      stage64x64(Vh + (it + 1) * 64, 2048, sV[cur ^ 1]);
    }
    const int kv0 = it * 64;
    attn_tile32(sK[cur], sV[cur], sP[w], qfh, aoh0, aoh1, mih, lih, wrow_hi, kv0, lane, offk, offv, offp);
    if (it < nt_lo)
      attn_tile32(sK[cur], sV[cur], sP[w], qfl, aol0, aol1, mil, lil, wrow_lo, kv0, lane, offk, offv, offp);
    cur ^= 1;
  }
  // epilogue: rows q' = wrow0 + (r&3)+8*(r>>2)+4*l5, col d = nd*32 + l31
  float rlh = 1.0f / lih, rll = 1.0f / lil;
#pragma unroll
  for (int r = 0; r < 16; ++r) {
    int qp = (r & 3) + 8 * (r >> 2) + 4 * l5;
    float fh = bperm_f(qp, rlh);
    float fl = bperm_f(qp, rll);
    size_t rowh = (size_t)b * 2048 + wrow_hi + qp;
    size_t rowl = (size_t)b * 2048 + wrow_lo + qp;
    int col = h * 64 + l31;
    Oh[rowh * 2048 + col]      = f2bf(aoh0[0][r] * fh);
    Oh[rowh * 2048 + col + 32] = f2bf(aoh1[0][r] * fh);
    Oh[rowl * 2048 + col]      = f2bf(aol0[0][r] * fl);
    Oh[rowl * 2048 + col + 32] = f2bf(aol1[0][r] * fl);
  }
}

__global__ __launch_bounds__(256) void outproj_kernel(const u16* __restrict__ A,
                                                      const u16* __restrict__ WoT,
                                                      float* __restrict__ out) {
  __shared__ __align__(16) u16 sA[2 * 4096];
  __shared__ __align__(16) u16 sB[2 * 4096];
  const int bm = blockIdx.x >> 4, bn = blockIdx.x & 15;
  f32x4 acc[4][4];
  gemm_tile(A, 2048, WoT, 2048, 2048, bm * 128, bn * 128, sA, sB, acc);
  const int t = threadIdx.x, w = t >> 6, lane = t & 63;
  const int wr = w >> 1, wc = w & 1, g = lane >> 4, r16 = lane & 15;
#pragma unroll
  for (int m = 0; m < 4; ++m)
#pragma unroll
    for (int n = 0; n < 4; ++n)
#pragma unroll
      for (int j = 0; j < 4; ++j) {
        int row = bm * 128 + wr * 64 + m * 16 + g * 4 + j;
        int col = bn * 128 + wc * 64 + n * 16 + r16;
        out[(size_t)row * 2048 + col] = acc[m][n][j];
      }
}

extern "C" void kernel_launch(void* const* d_in, const int* in_sizes, int n_in,
                              void* d_out, int out_size, void* d_ws, size_t ws_size,
                              hipStream_t stream) {
  const float* x  = (const float*)d_in[0];
  const float* wq = (const float*)d_in[1];
  const float* wk = (const float*)d_in[2];
  const float* wv = (const float*)d_in[3];
  const float* wo = (const float*)d_in[4];

  const size_t NEED_BYTES = 2ull * (8388608 + 4194304 + 1048576 + 1048576 + 4194304);
  if (ws_size < NEED_BYTES) return;

  float* outf  = (float*)d_out;
  float* koutf = outf + (size_t)8388608;
  float* voutf = koutf + (size_t)2097152;

  u16* Qs  = (u16*)d_out;                 // parked in out region
  u16* Vt  = Qs + (size_t)8388608;        // (B,HKV,HD,S)
  u16* Kbf = Vt + (size_t)2097152;        // (B,HKV,S,HD)

  u16* ws   = (u16*)d_ws;
  u16* xbf  = ws;                         // dead after proj -> reused as Oh
  u16* Oh   = ws;
  u16* wqT  = ws  + (size_t)8388608;
  u16* wkT  = wqT + (size_t)4194304;
  u16* wvT  = wkT + (size_t)1048576;
  u16* woT  = wvT + (size_t)1048576;

  cvt_kernel<<<4096, 256, 0, stream>>>(x, xbf);
  transpose_all<<<dim3(160, 64), dim3(32, 8), 0, stream>>>(wq, wk, wv, wo, wqT, wkT, wvT, woT);

  proj_kernel<<<768, 256, 0, stream>>>(xbf, wqT, wkT, wvT, Qs, koutf, Kbf, voutf, Vt);
  attn_kernel<<<512, 256, 0, stream>>>(Qs, Kbf, Vt, Oh);
  outproj_kernel<<<512, 256, 0, stream>>>(Oh, woT, outf);
}

// Round 14
// 233.759 us; speedup vs baseline: 1.7372x; 1.2079x over previous
//
#include <hip/hip_runtime.h>

typedef unsigned short u16;
typedef unsigned int u32;
typedef __attribute__((ext_vector_type(8))) __bf16 bf16x8;
typedef __attribute__((ext_vector_type(8))) u16 u16x8;
typedef __attribute__((ext_vector_type(2))) u32 u32x2;
typedef __attribute__((ext_vector_type(4))) float f32x4;
typedef __attribute__((ext_vector_type(16))) float f32x16;

#define DEVI static __device__ __forceinline__

// B=2, S=2048, D=2048, HQ=32, HKV=8, HD=64, G=4, KV_DIM=512, M=B*S=4096
// Inputs f32 (+int32 mask unused). Outputs f32 (out,K,V concat). bf16 internals.

DEVI u16 f2bf(float f) {
  unsigned u = __float_as_uint(f);
  u += 0x7fff + ((u >> 16) & 1);   // RNE
  return (u16)(u >> 16);
}

DEVI u32 cvt_pk_bf16(float lo, float hi) {
  u32 r;
  asm("v_cvt_pk_bf16_f32 %0, %1, %2" : "=v"(r) : "v"(lo), "v"(hi));
  return r;
}

DEVI float bperm_f(int srclane, float v) {
  return __int_as_float(__builtin_amdgcn_ds_bpermute(srclane << 2, __float_as_int(v)));
}

DEVI void gll16(const void* g, void* l) {
  __builtin_amdgcn_global_load_lds((const __attribute__((address_space(1))) void*)g,
                                   (__attribute__((address_space(3))) void*)l, 16, 0, 0);
}

// Stage 128x32 bf16 tile, XOR-swizzled via source (256-thread GEMM blocks).
DEVI void stage128x32(const u16* g, int ld, u16* lds) {
  int t = threadIdx.x, w = t >> 6, l = t & 63;
#pragma unroll
  for (int r = 0; r < 2; ++r) {
    int c = (w * 2 + r) * 64 + l;
    int row = c >> 2;
    int p = (c & 3) ^ (row & 3);
    gll16(g + (size_t)row * ld + p * 8, (char*)lds + (w * 2 + r) * 1024);
  }
}

// Stage 64x64 bf16 tile, XOR-swizzled (256 threads = 4 waves, 2 chunks/thread).
DEVI void stage64x64(const u16* g, int ld, u16* lds) {
  int t = threadIdx.x, w = t >> 6, l = t & 63;
#pragma unroll
  for (int r = 0; r < 2; ++r) {
    int c = (w * 2 + r) * 64 + l;
    int row = c >> 3;
    int p = (c & 7) ^ (row & 7);
    gll16(g + (size_t)row * ld + p * 8, (char*)lds + (w * 2 + r) * 1024);
  }
}

// 128x128 tile GEMM (unchanged, passing).
DEVI void gemm_tile(const u16* A, int lda, const u16* Bt, int ldb, int K,
                    int m0, int n0, u16* sA, u16* sB, f32x4 acc[4][4]) {
  const int t = threadIdx.x, w = t >> 6, lane = t & 63;
  const int wr = w >> 1, wc = w & 1, g = lane >> 4, r16 = lane & 15;
  int offa[4], offb[4];
#pragma unroll
  for (int m = 0; m < 4; ++m) {
    int row = wr * 64 + m * 16 + r16;
    offa[m] = row * 32 + ((g ^ (row & 3)) << 3);
  }
#pragma unroll
  for (int n = 0; n < 4; ++n) {
    int row = wc * 64 + n * 16 + r16;
    offb[n] = row * 32 + ((g ^ (row & 3)) << 3);
  }
#pragma unroll
  for (int m = 0; m < 4; ++m)
#pragma unroll
    for (int n = 0; n < 4; ++n) acc[m][n] = f32x4{0.f, 0.f, 0.f, 0.f};

  const u16* At = A + (size_t)m0 * lda;
  const u16* Bb = Bt + (size_t)n0 * ldb;
  stage128x32(At, lda, sA);
  stage128x32(Bb, ldb, sB);
  asm volatile("s_waitcnt vmcnt(0)" ::: "memory");
  __syncthreads();
  const int nk = K >> 5;
  int cur = 0;
  for (int kt = 0; kt < nk; ++kt) {
    if (kt + 1 < nk) {
      stage128x32(At + (kt + 1) * 32, lda, sA + (cur ^ 1) * 4096);
      stage128x32(Bb + (kt + 1) * 32, ldb, sB + (cur ^ 1) * 4096);
    }
    bf16x8 av[4], bv[4];
#pragma unroll
    for (int m = 0; m < 4; ++m) av[m] = *(const bf16x8*)(sA + cur * 4096 + offa[m]);
#pragma unroll
    for (int n = 0; n < 4; ++n) bv[n] = *(const bf16x8*)(sB + cur * 4096 + offb[n]);
#pragma unroll
    for (int m = 0; m < 4; ++m)
#pragma unroll
      for (int n = 0; n < 4; ++n)
        acc[m][n] = __builtin_amdgcn_mfma_f32_16x16x32_bf16(av[m], bv[n], acc[m][n], 0, 0, 0);
    asm volatile("s_waitcnt vmcnt(0)" ::: "memory");
    __syncthreads();
    cur ^= 1;
  }
}

__global__ __launch_bounds__(256) void cvt_kernel(const float* __restrict__ src,
                                                  u16* __restrict__ dst) {
  int i = blockIdx.x * 256 + threadIdx.x;
  float4 a = ((const float4*)src)[2 * i];
  float4 b = ((const float4*)src)[2 * i + 1];
  u16x8 o;
  o[0] = f2bf(a.x); o[1] = f2bf(a.y); o[2] = f2bf(a.z); o[3] = f2bf(a.w);
  o[4] = f2bf(b.x); o[5] = f2bf(b.y); o[6] = f2bf(b.z); o[7] = f2bf(b.w);
  ((u16x8*)dst)[i] = o;
}

__global__ __launch_bounds__(256) void transpose_all(
    const float* __restrict__ wq, const float* __restrict__ wk,
    const float* __restrict__ wv, const float* __restrict__ wo,
    u16* __restrict__ wqT, u16* __restrict__ wkT,
    u16* __restrict__ wvT, u16* __restrict__ woT) {
  __shared__ float tle[32][33];
  int bxr = blockIdx.x;
  const float* src; u16* dst; int C, bxl;
  if (bxr < 64)       { src = wq; dst = wqT; C = 2048; bxl = bxr; }
  else if (bxr < 80)  { src = wk; dst = wkT; C = 512;  bxl = bxr - 64; }
  else if (bxr < 96)  { src = wv; dst = wvT; C = 512;  bxl = bxr - 80; }
  else                { src = wo; dst = woT; C = 2048; bxl = bxr - 96; }
  int bx = bxl * 32, by = blockIdx.y * 32;
  int tx = threadIdx.x, ty = threadIdx.y;  // 32 x 8
#pragma unroll
  for (int i = 0; i < 32; i += 8) tle[ty + i][tx] = src[(size_t)(by + ty + i) * C + bx + tx];
  __syncthreads();
#pragma unroll
  for (int i = 0; i < 32; i += 8)
    dst[(size_t)(bx + ty + i) * 2048 + by + tx] = f2bf(tle[tx][ty + i]);
}

__global__ __launch_bounds__(256) void proj_kernel(
    const u16* __restrict__ x, const u16* __restrict__ wqT, const u16* __restrict__ wkT,
    const u16* __restrict__ wvT, u16* __restrict__ qout, float* __restrict__ koutf,
    u16* __restrict__ kbf, float* __restrict__ voutf, u16* __restrict__ vtout) {
  __shared__ __align__(16) u16 sA[2 * 4096];
  __shared__ __align__(16) u16 sB[2 * 4096];
  const int bid = blockIdx.x;
  int mode, bm, bn;
  const u16* Bt;
  if (bid < 512) { mode = 0; bm = bid >> 4; bn = bid & 15; Bt = wqT; }
  else if (bid < 640) { mode = 1; int i = bid - 512; bm = i >> 2; bn = i & 3; Bt = wkT; }
  else { mode = 2; int i = bid - 640; bm = i >> 2; bn = i & 3; Bt = wvT; }

  f32x4 acc[4][4];
  gemm_tile(x, 2048, Bt, 2048, 2048, bm * 128, bn * 128, sA, sB, acc);

  const int t = threadIdx.x, w = t >> 6, lane = t & 63;
  const int wr = w >> 1, wc = w & 1, g = lane >> 4, r16 = lane & 15;
  const float QSCALE = 0.125f * 1.44269504088896340736f;  // 1/sqrt(64) * log2(e)
#pragma unroll
  for (int m = 0; m < 4; ++m)
#pragma unroll
    for (int n = 0; n < 4; ++n)
#pragma unroll
      for (int j = 0; j < 4; ++j) {
        int row = bm * 128 + wr * 64 + m * 16 + g * 4 + j;
        int col = bn * 128 + wc * 64 + n * 16 + r16;
        float v = acc[m][n][j];
        if (mode == 0) {
          qout[(size_t)row * 2048 + col] = f2bf(v * QSCALE);
        } else {
          int b = row >> 11, s = row & 2047;
          int h = col >> 6, d = col & 63;
          size_t idx = ((size_t)(b * 8 + h) * 2048 + s) * 64 + d;
          if (mode == 1) {
            koutf[idx] = v;
            kbf[idx] = f2bf(v);
          } else {
            voutf[idx] = v;
            vtout[((size_t)(b * 8 + h) * 64 + d) * 2048 + s] = f2bf(v);
          }
        }
      }
}

// One 32-q-row x 64-kv tile, 32x32 swapped MFMA. P via per-wave swizzled LDS;
// cross-half reduce via __shfl_xor. (Byte-identical to passing r13.)
DEVI void attn_tile32(const u16* sKc, const u16* sVc, u16* sPw,
                      const bf16x8 (&qf)[4], f32x16 (&accO0)[1], f32x16 (&accO1)[1],
                      float &mi, float &li,
                      int wrow0, int kv0, int lane,
                      const int (&offk)[2][4], const int (&offv)[4][2],
                      const int (&offp)[4]) {
  if (kv0 > wrow0 + 31) return;
  const int l5 = lane >> 5, l31 = lane & 31;
  f32x16 st[2];
#pragma unroll
  for (int i = 0; i < 16; ++i) { st[0][i] = 0.f; st[1][i] = 0.f; }
  __builtin_amdgcn_s_setprio(1);
#pragma unroll
  for (int kd = 0; kd < 4; ++kd)
#pragma unroll
    for (int kb = 0; kb < 2; ++kb) {
      bf16x8 kf = *(const bf16x8*)(sKc + offk[kb][kd]);
      st[kb] = __builtin_amdgcn_mfma_f32_32x32x16_bf16(kf, qf[kd], st[kb], 0, 0, 0);
    }
  __builtin_amdgcn_s_setprio(0);
  if (kv0 + 63 > wrow0) {  // diagonal: causal mask
    int qg = wrow0 + l31;
#pragma unroll
    for (int kb = 0; kb < 2; ++kb)
#pragma unroll
      for (int r = 0; r < 16; ++r) {
        int kvg = kv0 + kb * 32 + (r & 3) + 8 * (r >> 2) + 4 * l5;
        if (kvg > qg) st[kb][r] = -1e30f;
      }
  }
  float pmax = st[0][0];
#pragma unroll
  for (int r = 1; r < 16; ++r) pmax = fmaxf(pmax, st[0][r]);
#pragma unroll
  for (int r = 0; r < 16; ++r) pmax = fmaxf(pmax, st[1][r]);
  pmax = fmaxf(pmax, __shfl_xor(pmax, 32));
  // defer-max: rescale only when running max grows by >8 (exp2 domain)
  if (!__all(pmax - mi <= 8.0f)) {
    float mn = fmaxf(mi, pmax);
    float scl = exp2f(mi - mn);
    mi = mn; li *= scl;
#pragma unroll
    for (int r = 0; r < 16; ++r) {
      int qp = (r & 3) + 8 * (r >> 2) + 4 * l5;
      float sj = bperm_f(qp, scl);
      accO0[0][r] *= sj;
      accO1[0][r] *= sj;
    }
  }
  float rs = 0.f;
#pragma unroll
  for (int kb = 0; kb < 2; ++kb)
#pragma unroll
    for (int r = 0; r < 16; ++r) { st[kb][r] = exp2f(st[kb][r] - mi); rs += st[kb][r]; }
  rs += __shfl_xor(rs, 32);
  li += rs;
  // P -> per-wave LDS, XOR-swizzled. Lane holds P[q=l31][kv = kb*32+8t+4*l5 .. +3]
  {
    u16* base = sPw + l31 * 64;
#pragma unroll
    for (int kb = 0; kb < 2; ++kb)
#pragma unroll
      for (int tt = 0; tt < 4; ++tt) {
        u32 lo = cvt_pk_bf16(st[kb][4 * tt + 0], st[kb][4 * tt + 1]);
        u32 hi = cvt_pk_bf16(st[kb][4 * tt + 2], st[kb][4 * tt + 3]);
        int chunk = kb * 4 + tt;
        u32x2 w2 = {lo, hi};
        *(u32x2*)(base + ((chunk ^ (l31 & 7)) << 3) + l5 * 4) = w2;
      }
  }
  asm volatile("s_waitcnt lgkmcnt(0)" ::: "memory");
  __builtin_amdgcn_s_setprio(1);
#pragma unroll
  for (int ks = 0; ks < 4; ++ks) {
    bf16x8 pa = *(const bf16x8*)(sPw + offp[ks]);
    bf16x8 v0 = *(const bf16x8*)(sVc + offv[ks][0]);
    bf16x8 v1 = *(const bf16x8*)(sVc + offv[ks][1]);
    accO0[0] = __builtin_amdgcn_mfma_f32_32x32x16_bf16(pa, v0, accO0[0], 0, 0, 0);
    accO1[0] = __builtin_amdgcn_mfma_f32_32x32x16_bf16(pa, v1, accO1[0], 0, 0, 0);
  }
  __builtin_amdgcn_s_setprio(0);
}

// One q-tile (128 rows) per 4-wave block. Grid 1024 = 3 blocks/CU co-resident.
// LPT: heavy q-tiles dispatch first per XCD stream; (b,hkv) pinned per XCD.
__global__ __launch_bounds__(256) void attn_kernel(
    const u16* __restrict__ Q, const u16* __restrict__ Kp,
    const u16* __restrict__ Vt, u16* __restrict__ Oh) {
  __shared__ __align__(16) u16 sK[2][4096];
  __shared__ __align__(16) u16 sV[2][4096];
  __shared__ __align__(16) u16 sP[4][2048];
  const int bid = blockIdx.x;
  const int xcd = bid & 7, rank = bid >> 3;
  const int qb = 15 - (rank >> 3);              // heavy first within each XCD stream
  const int sub = rank & 7;
  const int bhkv = xcd * 2 + (sub >> 2);        // (b,hkv) pinned to XCD
  const int b = bhkv >> 3, hkv = bhkv & 7;
  const int h = hkv * 4 + (sub & 3);
  const int t = threadIdx.x, w = t >> 6, lane = t & 63;
  const int l5 = lane >> 5, l31 = lane & 31;
  const int wrow0 = qb * 128 + w * 32;

  int offk[2][4], offv[4][2], offp[4];
#pragma unroll
  for (int kb = 0; kb < 2; ++kb) {
    int row = kb * 32 + l31;
#pragma unroll
    for (int kd = 0; kd < 4; ++kd)
      offk[kb][kd] = row * 64 + (((kd * 2 + l5) ^ (row & 7)) << 3);
  }
#pragma unroll
  for (int ks = 0; ks < 4; ++ks) {
    offp[ks] = l31 * 64 + (((ks * 2 + l5) ^ (l31 & 7)) << 3);
#pragma unroll
    for (int nd = 0; nd < 2; ++nd) {
      int rd = nd * 32 + l31;
      offv[ks][nd] = rd * 64 + (((ks * 2 + l5) ^ (rd & 7)) << 3);
    }
  }

  const u16* Qb = Q + (size_t)b * 2048 * 2048 + h * 64 + l5 * 8;
  bf16x8 qf[4];
#pragma unroll
  for (int kd = 0; kd < 4; ++kd)
    qf[kd] = *(const bf16x8*)(Qb + (size_t)(wrow0 + l31) * 2048 + kd * 16);

  const u16* Kh = Kp + (size_t)(b * 8 + hkv) * 2048 * 64;
  const u16* Vh = Vt + (size_t)(b * 8 + hkv) * 64 * 2048;

  f32x16 ao0[1], ao1[1];
#pragma unroll
  for (int i = 0; i < 16; ++i) { ao0[0][i] = 0.f; ao1[0][i] = 0.f; }
  float mi = -1e30f, li = 0.f;

  const int nt = 2 * (qb + 1);
  int cur = 0;
  stage64x64(Kh, 64, sK[0]);
  stage64x64(Vh, 2048, sV[0]);
  for (int it = 0; it < nt; ++it) {
    asm volatile("s_waitcnt vmcnt(0)" ::: "memory");
    __syncthreads();
    if (it + 1 < nt) {
      stage64x64(Kh + (size_t)(it + 1) * 64 * 64, 64, sK[cur ^ 1]);
      stage64x64(Vh + (it + 1) * 64, 2048, sV[cur ^ 1]);
    }
    const int kv0 = it * 64;
    attn_tile32(sK[cur], sV[cur], sP[w], qf, ao0, ao1, mi, li, wrow0, kv0, lane, offk, offv, offp);
    cur ^= 1;
  }
  // epilogue: rows q' = wrow0 + (r&3)+8*(r>>2)+4*l5, col d = nd*32 + l31
  float rl = 1.0f / li;
#pragma unroll
  for (int r = 0; r < 16; ++r) {
    int qp = (r & 3) + 8 * (r >> 2) + 4 * l5;
    float f = bperm_f(qp, rl);
    size_t row = (size_t)b * 2048 + wrow0 + qp;
    int col = h * 64 + l31;
    Oh[row * 2048 + col]      = f2bf(ao0[0][r] * f);
    Oh[row * 2048 + col + 32] = f2bf(ao1[0][r] * f);
  }
}

__global__ __launch_bounds__(256) void outproj_kernel(const u16* __restrict__ A,
                                                      const u16* __restrict__ WoT,
                                                      float* __restrict__ out) {
  __shared__ __align__(16) u16 sA[2 * 4096];
  __shared__ __align__(16) u16 sB[2 * 4096];
  const int bm = blockIdx.x >> 4, bn = blockIdx.x & 15;
  f32x4 acc[4][4];
  gemm_tile(A, 2048, WoT, 2048, 2048, bm * 128, bn * 128, sA, sB, acc);
  const int t = threadIdx.x, w = t >> 6, lane = t & 63;
  const int wr = w >> 1, wc = w & 1, g = lane >> 4, r16 = lane & 15;
#pragma unroll
  for (int m = 0; m < 4; ++m)
#pragma unroll
    for (int n = 0; n < 4; ++n)
#pragma unroll
      for (int j = 0; j < 4; ++j) {
        int row = bm * 128 + wr * 64 + m * 16 + g * 4 + j;
        int col = bn * 128 + wc * 64 + n * 16 + r16;
        out[(size_t)row * 2048 + col] = acc[m][n][j];
      }
}

extern "C" void kernel_launch(void* const* d_in, const int* in_sizes, int n_in,
                              void* d_out, int out_size, void* d_ws, size_t ws_size,
                              hipStream_t stream) {
  const float* x  = (const float*)d_in[0];
  const float* wq = (const float*)d_in[1];
  const float* wk = (const float*)d_in[2];
  const float* wv = (const float*)d_in[3];
  const float* wo = (const float*)d_in[4];

  const size_t NEED_BYTES = 2ull * (8388608 + 4194304 + 1048576 + 1048576 + 4194304);
  if (ws_size < NEED_BYTES) return;

  float* outf  = (float*)d_out;
  float* koutf = outf + (size_t)8388608;
  float* voutf = koutf + (size_t)2097152;

  u16* Qs  = (u16*)d_out;                 // parked in out region
  u16* Vt  = Qs + (size_t)8388608;        // (B,HKV,HD,S)
  u16* Kbf = Vt + (size_t)2097152;        // (B,HKV,S,HD)

  u16* ws   = (u16*)d_ws;
  u16* xbf  = ws;                         // dead after proj -> reused as Oh
  u16* Oh   = ws;
  u16* wqT  = ws  + (size_t)8388608;
  u16* wkT  = wqT + (size_t)4194304;
  u16* wvT  = wkT + (size_t)1048576;
  u16* woT  = wvT + (size_t)1048576;

  cvt_kernel<<<4096, 256, 0, stream>>>(x, xbf);
  transpose_all<<<dim3(160, 64), dim3(32, 8), 0, stream>>>(wq, wk, wv, wo, wqT, wkT, wvT, woT);

  proj_kernel<<<768, 256, 0, stream>>>(xbf, wqT, wkT, wvT, Qs, koutf, Kbf, voutf, Vt);
  attn_kernel<<<1024, 256, 0, stream>>>(Qs, Kbf, Vt, Oh);
  outproj_kernel<<<512, 256, 0, stream>>>(Oh, woT, outf);
}